// Round 5
// baseline (938.892 us; speedup 1.0000x reference)
//
#include <hip/hip_runtime.h>

#define KDIM 256
#define NB 16384
#define NR 8192
#define KP 768          // concatenated K' = 3 products x 256

typedef unsigned short ushort_t;
typedef __attribute__((ext_vector_type(8))) short short8;
typedef __attribute__((ext_vector_type(4))) float f32x4;

// ---------------------------------------------------------------- helpers ---
__device__ __forceinline__ ushort_t f2bf(float f) {          // RNE f32->bf16
    unsigned u = __float_as_uint(f);
    unsigned r = (u + 0x7fffu + ((u >> 16) & 1u)) >> 16;
    return (ushort_t)r;
}
__device__ __forceinline__ float bf2f(ushort_t s) {
    return __uint_as_float(((unsigned)s) << 16);
}
__device__ __forceinline__ void gload16(const void* g, void* l) {
    __builtin_amdgcn_global_load_lds(
        (const __attribute__((address_space(1))) void*)g,
        (__attribute__((address_space(3))) void*)l, 16, 0, 0);
}
// branchless insert into sorted top-3 (v desc, idx asc on ties)
__device__ __forceinline__ void ins3(float v, int idx,
                                     float& v0, int& i0, float& v1, int& i1,
                                     float& v2, int& i2) {
    bool b0 = (v > v0) | ((v == v0) & (idx < i0));
    bool b1 = (v > v1) | ((v == v1) & (idx < i1));
    bool b2 = (v > v2) | ((v == v2) & (idx < i2));
    float nv2 = b1 ? v1 : (b2 ? v : v2);
    int   ni2 = b1 ? i1 : (b2 ? idx : i2);
    float nv1 = b0 ? v0 : (b1 ? v : v1);
    int   ni1 = b0 ? i0 : (b1 ? idx : i1);
    float nv0 = b0 ? v : v0;
    int   ni0 = b0 ? idx : i0;
    v0 = nv0; i0 = ni0; v1 = nv1; i1 = ni1; v2 = nv2; i2 = ni2;
}
// branchless insert into sorted top-4
__device__ __forceinline__ void ins4(float v, int idx,
                                     float& v0, int& i0, float& v1, int& i1,
                                     float& v2, int& i2, float& v3, int& i3) {
    bool b0 = (v > v0) | ((v == v0) & (idx < i0));
    bool b1 = (v > v1) | ((v == v1) & (idx < i1));
    bool b2 = (v > v2) | ((v == v2) & (idx < i2));
    bool b3 = (v > v3) | ((v == v3) & (idx < i3));
    float nv3 = b2 ? v2 : (b3 ? v : v3);
    int   ni3 = b2 ? i2 : (b3 ? idx : i3);
    float nv2 = b1 ? v1 : (b2 ? v : v2);
    int   ni2 = b1 ? i1 : (b2 ? idx : i2);
    float nv1 = b0 ? v0 : (b1 ? v : v1);
    int   ni1 = b0 ? i0 : (b1 ? idx : i1);
    float nv0 = b0 ? v : v0;
    int   ni0 = b0 ? idx : i0;
    v0 = nv0; i0 = ni0; v1 = nv1; i1 = ni1; v2 = nv2; i2 = ni2; v3 = nv3; i3 = ni3;
}

// ----------------- split: normalize + 2-way bf16 split, K-concatenated ------
// A' row = [h | h | m]   B' row = [h | m | h]   =>  A'.B' = hh + hm + mh
__global__ __launch_bounds__(256) void split2_kernel(
    const float* __restrict__ base, const float* __restrict__ real,
    ushort_t* __restrict__ Ap, ushort_t* __restrict__ Bp,
    float* __restrict__ inv) {
    int rid  = blockIdx.x * 4 + (threadIdx.x >> 6);
    int lane = threadIdx.x & 63;
    bool isA = rid < NB;
    int  row = isA ? rid : rid - NB;
    const float* src = isA ? base + (size_t)row * KDIM : real + (size_t)row * KDIM;
    float4 v = *(const float4*)(src + lane * 4);
    float ss = v.x * v.x + v.y * v.y + v.z * v.z + v.w * v.w;
    #pragma unroll
    for (int off = 32; off > 0; off >>= 1) ss += __shfl_xor(ss, off);
    float invn = 1.0f / fmaxf(sqrtf(ss), 1e-12f);

    float n[4] = {v.x * invn, v.y * invn, v.z * invn, v.w * invn};
    ushort_t h[4], m[4];
    #pragma unroll
    for (int e = 0; e < 4; ++e) {
        h[e] = f2bf(n[e]);
        m[e] = f2bf(n[e] - bf2f(h[e]));
    }
    ushort4 h4 = make_ushort4(h[0], h[1], h[2], h[3]);
    ushort4 m4 = make_ushort4(m[0], m[1], m[2], m[3]);
    ushort_t* d = (isA ? Ap : Bp) + (size_t)row * KP + lane * 4;
    *(ushort4*)(d)       = h4;
    *(ushort4*)(d + 256) = isA ? h4 : m4;
    *(ushort4*)(d + 512) = isA ? m4 : h4;
    if (lane == 0) inv[rid] = invn;
}

// --------------------- fused bf16 MFMA GEMM (K'=768) + per-block top-4 ------
// block 256 thr = 4 waves (2x2), tile 128x128, BK=64, 12 K-iterations.
__global__ __launch_bounds__(256) void mfma_topk_kernel(
    const ushort_t* __restrict__ Ap, const ushort_t* __restrict__ Bp,
    float* __restrict__ Pv, int* __restrict__ Pi) {
    __shared__ ushort_t sA[128 * 64];
    __shared__ ushort_t sB[128 * 64];

    const int tid  = threadIdx.x;
    const int lane = tid & 63;
    const int w    = tid >> 6;
    const int wr   = w >> 1, wc = w & 1;
    const int c    = lane & 15;       // frag col/row-in-16
    const int kg   = lane >> 4;       // frag k-group (0..3)
    const int lr8  = lane >> 3;       // staging: row within 8-row chunk
    const int ud   = lane & 7;        // staging: 16B slot within row (linear)

    // ---- bijective XCD supertile remap: 8192 blocks = 8 XCD x 16 st x 8x8 --
    int lin = blockIdx.y * 64 + blockIdx.x;     // gridDim = (64, 128)
    int xcd = lin & 7;
    int pos = lin >> 3;                          // 0..1023
    int gg  = xcd * 1024 + pos;                  // chunked per-XCD range
    int st  = gg >> 6, in8 = gg & 63;            // supertile id, pos within
    int my  = ((st >> 3) << 3) + (in8 >> 3);     // 0..127 row tile
    int nx  = ((st & 7) << 3) + (in8 & 7);       // 0..63  col tile
    const int m0 = my * 128;
    const int n0 = nx * 128;

    f32x4 acc[4][4];
    #pragma unroll
    for (int i = 0; i < 4; ++i)
        #pragma unroll
        for (int j = 0; j < 4; ++j) acc[i][j] = (f32x4){0.f, 0.f, 0.f, 0.f};

    #pragma unroll 1
    for (int kc = 0; kc < KP; kc += 64) {
        __syncthreads();   // LDS free (prev compute done)
        #pragma unroll
        for (int q = 0; q < 4; ++q) {
            int R = (w * 4 + q) * 8;           // 8-row chunk base
            gload16(Ap + (size_t)(m0 + R + lr8) * KP + kc + ud * 8,
                    (char*)sA + R * 128);
            gload16(Bp + (size_t)(n0 + R + lr8) * KP + kc + ud * 8,
                    (char*)sB + R * 128);
        }
        __syncthreads();   // staging complete
        #pragma unroll
        for (int kk = 0; kk < 2; ++kk) {
            short8 a[4], b[4];
            int u = kk * 4 + kg;
            #pragma unroll
            for (int i = 0; i < 4; ++i) {
                int ra = wr * 64 + i * 16 + c;
                a[i] = *(const short8*)(sA + ra * 64 + u * 8);
                int rb = wc * 64 + i * 16 + c;
                b[i] = *(const short8*)(sB + rb * 64 + u * 8);
            }
            #pragma unroll
            for (int i = 0; i < 4; ++i)
                #pragma unroll
                for (int j = 0; j < 4; ++j)
                    acc[i][j] = __builtin_amdgcn_mfma_f32_16x16x32_bf16(
                        a[i], b[j], acc[i][j], 0, 0, 0);
        }
    }

    // ---- per-row top-4 over this block's 128 cols ----
    __syncthreads();                       // done reading tiles; reuse LDS
    float* mv = (float*)sA;                // [128][2][4]
    int*   mi = (int*)sB;
    #pragma unroll
    for (int i = 0; i < 4; ++i) {
        #pragma unroll
        for (int r = 0; r < 4; ++r) {
            float v0 = -3.0e38f, v1 = -3.0e38f, v2 = -3.0e38f, v3 = -3.0e38f;
            int   i0 = 0x7fffffff, i1 = 0x7fffffff, i2 = 0x7fffffff, i3 = 0x7fffffff;
            #pragma unroll
            for (int j = 0; j < 4; ++j)
                ins4(acc[i][j][r], n0 + wc * 64 + j * 16 + c,
                     v0, i0, v1, i1, v2, i2, v3, i3);
            #pragma unroll
            for (int mask = 1; mask <= 8; mask <<= 1) {
                float ov0 = __shfl_xor(v0, mask), ov1 = __shfl_xor(v1, mask),
                      ov2 = __shfl_xor(v2, mask), ov3 = __shfl_xor(v3, mask);
                int   oi0 = __shfl_xor(i0, mask), oi1 = __shfl_xor(i1, mask),
                      oi2 = __shfl_xor(i2, mask), oi3 = __shfl_xor(i3, mask);
                ins4(ov0, oi0, v0, i0, v1, i1, v2, i2, v3, i3);
                ins4(ov1, oi1, v0, i0, v1, i1, v2, i2, v3, i3);
                ins4(ov2, oi2, v0, i0, v1, i1, v2, i2, v3, i3);
                ins4(ov3, oi3, v0, i0, v1, i1, v2, i2, v3, i3);
            }
            if (c == 0) {
                int row = wr * 64 + i * 16 + kg * 4 + r;
                float* pv = &mv[(row * 2 + wc) * 4];
                int*   pi = &mi[(row * 2 + wc) * 4];
                pv[0] = v0; pv[1] = v1; pv[2] = v2; pv[3] = v3;
                pi[0] = i0; pi[1] = i1; pi[2] = i2; pi[3] = i3;
            }
        }
    }
    __syncthreads();
    if (tid < 128) {
        float v0 = -3.0e38f, v1 = -3.0e38f, v2 = -3.0e38f, v3 = -3.0e38f;
        int   i0 = 0x7fffffff, i1 = 0x7fffffff, i2 = 0x7fffffff, i3 = 0x7fffffff;
        #pragma unroll
        for (int e = 0; e < 8; ++e)
            ins4(mv[tid * 8 + e], mi[tid * 8 + e], v0, i0, v1, i1, v2, i2, v3, i3);
        size_t o = (size_t)(m0 + tid) * 256 + nx * 4;   // [row][64 blocks][4]
        *(float4*)&Pv[o] = make_float4(v0, v1, v2, v3);
        *(int4*)  &Pi[o] = make_int4(i0, i1, i2, i3);
    }
}

// ---- stage-2: butterfly-merge 64x4 partials -> row top-4, exact f32 rerank -
// Rerank reproduces round-1's exact arithmetic: per element round(a*ia),
// round(b*ib), then a strict sequential fmaf chain in k order.
__global__ __launch_bounds__(256) void merge3_kernel(
    const float* __restrict__ Pv, const int* __restrict__ Pi,
    const float* __restrict__ base, const float* __restrict__ real,
    const float* __restrict__ inv, int* __restrict__ out) {
    int row  = blockIdx.x * 4 + (threadIdx.x >> 6);
    int lane = threadIdx.x & 63;
    float4 pv = *(const float4*)(Pv + (size_t)row * 256 + lane * 4);
    int4   pi = *(const int4*)  (Pi + (size_t)row * 256 + lane * 4);

    float v0 = -3.0e38f, v1 = -3.0e38f, v2 = -3.0e38f, v3 = -3.0e38f;
    int   i0 = 0x7fffffff, i1 = 0x7fffffff, i2 = 0x7fffffff, i3 = 0x7fffffff;
    ins4(pv.x, pi.x, v0, i0, v1, i1, v2, i2, v3, i3);
    ins4(pv.y, pi.y, v0, i0, v1, i1, v2, i2, v3, i3);
    ins4(pv.z, pi.z, v0, i0, v1, i1, v2, i2, v3, i3);
    ins4(pv.w, pi.w, v0, i0, v1, i1, v2, i2, v3, i3);
    #pragma unroll
    for (int mask = 1; mask <= 32; mask <<= 1) {
        float ov0 = __shfl_xor(v0, mask), ov1 = __shfl_xor(v1, mask),
              ov2 = __shfl_xor(v2, mask), ov3 = __shfl_xor(v3, mask);
        int   oi0 = __shfl_xor(i0, mask), oi1 = __shfl_xor(i1, mask),
              oi2 = __shfl_xor(i2, mask), oi3 = __shfl_xor(i3, mask);
        ins4(ov0, oi0, v0, i0, v1, i1, v2, i2, v3, i3);
        ins4(ov1, oi1, v0, i0, v1, i1, v2, i2, v3, i3);
        ins4(ov2, oi2, v0, i0, v1, i1, v2, i2, v3, i3);
        ins4(ov3, oi3, v0, i0, v1, i1, v2, i2, v3, i3);
    }
    // all lanes now hold the row's approx top-4 (identical across lanes)
    int cand = (lane == 0) ? i0 : (lane == 1) ? i1 : (lane == 2) ? i2 : i3;
    float s = 0.0f;
    if (lane < 4) {
        const float* a = base + (size_t)row  * KDIM;
        const float* b = real + (size_t)cand * KDIM;
        float ia = inv[row], ib = inv[NB + cand];
        #pragma unroll 4
        for (int k = 0; k < KDIM; k += 4) {
            float4 av = *(const float4*)(a + k);
            float4 bv = *(const float4*)(b + k);
            s = fmaf(av.x * ia, bv.x * ib, s);
            s = fmaf(av.y * ia, bv.y * ib, s);
            s = fmaf(av.z * ia, bv.z * ib, s);
            s = fmaf(av.w * ia, bv.w * ib, s);
        }
    }
    // gather the 4 exact scores, pick top-3
    float fv0 = -3.0e38f, fv1 = -3.0e38f, fv2 = -3.0e38f;
    int   fi0 = 0x7fffffff, fi1 = 0x7fffffff, fi2 = 0x7fffffff;
    #pragma unroll
    for (int l = 0; l < 4; ++l) {
        float sv = __shfl(s, l);
        int   si = __shfl(cand, l);
        ins3(sv, si, fv0, fi0, fv1, fi1, fv2, fi2);
    }
    if (lane == 0) {
        out[row * 3 + 0] = fi0;
        out[row * 3 + 1] = fi1;
        out[row * 3 + 2] = fi2;
    }
}

// ======================= fallback (round-1 f32 path) ========================
__global__ __launch_bounds__(256) void norm_kernel(const float* __restrict__ base,
                                                   const float* __restrict__ real,
                                                   float* __restrict__ inv) {
    int rid  = blockIdx.x * 4 + (threadIdx.x >> 6);
    int lane = threadIdx.x & 63;
    if (rid >= NB + NR) return;
    const float* src = (rid < NB) ? (base + (size_t)rid * KDIM)
                                  : (real + (size_t)(rid - NB) * KDIM);
    float4 v = *(const float4*)(src + lane * 4);
    float ss = v.x * v.x + v.y * v.y + v.z * v.z + v.w * v.w;
    #pragma unroll
    for (int off = 32; off > 0; off >>= 1) ss += __shfl_xor(ss, off);
    if (lane == 0) inv[rid] = 1.0f / fmaxf(sqrtf(ss), 1e-12f);
}

#define DOT(i, j, av, bv)                                                      \
    acc[i][j] = fmaf(av.x, bv.x, acc[i][j]);                                   \
    acc[i][j] = fmaf(av.y, bv.y, acc[i][j]);                                   \
    acc[i][j] = fmaf(av.z, bv.z, acc[i][j]);                                   \
    acc[i][j] = fmaf(av.w, bv.w, acc[i][j]);

__global__ __launch_bounds__(256) void simtopk_kernel(
    const float* __restrict__ A, const float* __restrict__ B,
    const float* __restrict__ invA, const float* __restrict__ invB,
    int* __restrict__ out) {
    __shared__ float sA[64 * 68];
    __shared__ float sB[64 * 68];
    const int tid = threadIdx.x;
    const int tx  = tid & 15;
    const int ty4 = (tid >> 4) << 2;
    const int m0  = blockIdx.x * 64;
    float t3v[4][3];
    int   t3i[4][3];
    #pragma unroll
    for (int i = 0; i < 4; ++i)
        #pragma unroll
        for (int s = 0; s < 3; ++s) { t3v[i][s] = -3.0e38f; t3i[i][s] = 0x7fffffff; }
    for (int nn0 = 0; nn0 < NR; nn0 += 64) {
        float acc[4][4] = {{0.f}};
        for (int kc = 0; kc < KDIM; kc += 64) {
            __syncthreads();
            #pragma unroll
            for (int p = 0; p < 4; ++p) {
                int f = tid + (p << 8), row = f >> 4, c4 = (f & 15) << 2;
                float4 va = *(const float4*)(A + (size_t)(m0 + row) * KDIM + kc + c4);
                float  sa = invA[m0 + row];
                va.x *= sa; va.y *= sa; va.z *= sa; va.w *= sa;
                *(float4*)&sA[row * 68 + c4] = va;
                float4 vb = *(const float4*)(B + (size_t)(nn0 + row) * KDIM + kc + c4);
                float  sb = invB[nn0 + row];
                vb.x *= sb; vb.y *= sb; vb.z *= sb; vb.w *= sb;
                *(float4*)&sB[row * 68 + c4] = vb;
            }
            __syncthreads();
            #pragma unroll
            for (int k = 0; k < 64; k += 4) {
                float4 a0 = *(const float4*)&sA[(ty4 + 0) * 68 + k];
                float4 a1 = *(const float4*)&sA[(ty4 + 1) * 68 + k];
                float4 a2 = *(const float4*)&sA[(ty4 + 2) * 68 + k];
                float4 a3 = *(const float4*)&sA[(ty4 + 3) * 68 + k];
                float4 b0 = *(const float4*)&sB[(tx +  0) * 68 + k];
                float4 b1 = *(const float4*)&sB[(tx + 16) * 68 + k];
                float4 b2 = *(const float4*)&sB[(tx + 32) * 68 + k];
                float4 b3 = *(const float4*)&sB[(tx + 48) * 68 + k];
                DOT(0,0,a0,b0) DOT(0,1,a0,b1) DOT(0,2,a0,b2) DOT(0,3,a0,b3)
                DOT(1,0,a1,b0) DOT(1,1,a1,b1) DOT(1,2,a1,b2) DOT(1,3,a1,b3)
                DOT(2,0,a2,b0) DOT(2,1,a2,b1) DOT(2,2,a2,b2) DOT(2,3,a2,b3)
                DOT(3,0,a3,b0) DOT(3,1,a3,b1) DOT(3,2,a3,b2) DOT(3,3,a3,b3)
            }
        }
        #pragma unroll
        for (int i = 0; i < 4; ++i)
            #pragma unroll
            for (int j = 0; j < 4; ++j)
                ins3(acc[i][j], nn0 + tx + 16 * j,
                     t3v[i][0], t3i[i][0], t3v[i][1], t3i[i][1], t3v[i][2], t3i[i][2]);
    }
    __syncthreads();
    float* mv = sA;
    int*   mi = (int*)sB;
    #pragma unroll
    for (int i = 0; i < 4; ++i)
        #pragma unroll
        for (int s = 0; s < 3; ++s) {
            mv[(ty4 + i) * 48 + tx * 3 + s] = t3v[i][s];
            mi[(ty4 + i) * 48 + tx * 3 + s] = t3i[i][s];
        }
    __syncthreads();
    if (tid < 64) {
        float v0 = -3.0e38f, v1 = -3.0e38f, v2 = -3.0e38f;
        int   i0 = 0x7fffffff, i1 = 0x7fffffff, i2 = 0x7fffffff;
        for (int e = 0; e < 48; ++e)
            ins3(mv[tid * 48 + e], mi[tid * 48 + e], v0, i0, v1, i1, v2, i2);
        out[(m0 + tid) * 3 + 0] = i0;
        out[(m0 + tid) * 3 + 1] = i1;
        out[(m0 + tid) * 3 + 2] = i2;
    }
}

// ============================================================== launcher ====
extern "C" void kernel_launch(void* const* d_in, const int* in_sizes, int n_in,
                              void* d_out, int out_size, void* d_ws, size_t ws_size,
                              hipStream_t stream) {
    const float* base = (const float*)d_in[0];
    const float* real = (const float*)d_in[1];
    int* out = (int*)d_out;

    const size_t szAp  = (size_t)NB * KP * 2;        // 25.2 MB
    const size_t szBp  = (size_t)NR * KP * 2;        // 12.6 MB
    const size_t szPv  = (size_t)NB * 256 * 4;       // 16.8 MB
    const size_t szInv = (size_t)(NB + NR) * 4;      // 0.1 MB
    const size_t need  = szAp + szBp + 2 * szPv + szInv;

    if (ws_size >= need) {
        char* p = (char*)d_ws;
        ushort_t* Ap  = (ushort_t*)(p);
        ushort_t* Bp  = (ushort_t*)(p + szAp);
        float*    Pv  = (float*)   (p + szAp + szBp);
        int*      Pi  = (int*)     (p + szAp + szBp + szPv);
        float*    inv = (float*)   (p + szAp + szBp + 2 * szPv);

        hipLaunchKernelGGL(split2_kernel, dim3((NB + NR) / 4), dim3(256), 0, stream,
                           base, real, Ap, Bp, inv);
        hipLaunchKernelGGL(mfma_topk_kernel, dim3(NR / 128, NB / 128), dim3(256), 0,
                           stream, Ap, Bp, Pv, Pi);
        hipLaunchKernelGGL(merge3_kernel, dim3(NB / 4), dim3(256), 0, stream,
                           Pv, Pi, base, real, inv, out);
    } else {
        float* inv = (float*)d_ws;
        hipLaunchKernelGGL(norm_kernel, dim3((NB + NR) / 4), dim3(256), 0, stream,
                           base, real, inv);
        hipLaunchKernelGGL(simtopk_kernel, dim3(NB / 64), dim3(256), 0, stream,
                           base, real, inv, inv + NB, out);
    }
}

// Round 6
// 544.009 us; speedup vs baseline: 1.7259x; 1.7259x over previous
//
#include <hip/hip_runtime.h>

#define KDIM 256
#define NB 16384
#define NR 8192
#define KP 768          // concatenated K' = 3 products x 256

typedef unsigned short ushort_t;
typedef __attribute__((ext_vector_type(8))) short short8;
typedef __attribute__((ext_vector_type(4))) float f32x4;

// ---------------------------------------------------------------- helpers ---
__device__ __forceinline__ ushort_t f2bf(float f) {          // RNE f32->bf16
    unsigned u = __float_as_uint(f);
    unsigned r = (u + 0x7fffu + ((u >> 16) & 1u)) >> 16;
    return (ushort_t)r;
}
__device__ __forceinline__ float bf2f(ushort_t s) {
    return __uint_as_float(((unsigned)s) << 16);
}
__device__ __forceinline__ void gload16(const void* g, void* l) {
    __builtin_amdgcn_global_load_lds(
        (const __attribute__((address_space(1))) void*)g,
        (__attribute__((address_space(3))) void*)l, 16, 0, 0);
}
// branchless insert into sorted top-3 (v desc, idx asc on ties)
__device__ __forceinline__ void ins3(float v, int idx,
                                     float& v0, int& i0, float& v1, int& i1,
                                     float& v2, int& i2) {
    bool b0 = (v > v0) | ((v == v0) & (idx < i0));
    bool b1 = (v > v1) | ((v == v1) & (idx < i1));
    bool b2 = (v > v2) | ((v == v2) & (idx < i2));
    float nv2 = b1 ? v1 : (b2 ? v : v2);
    int   ni2 = b1 ? i1 : (b2 ? idx : i2);
    float nv1 = b0 ? v0 : (b1 ? v : v1);
    int   ni1 = b0 ? i0 : (b1 ? idx : i1);
    float nv0 = b0 ? v : v0;
    int   ni0 = b0 ? idx : i0;
    v0 = nv0; i0 = ni0; v1 = nv1; i1 = ni1; v2 = nv2; i2 = ni2;
}
// branchless insert into sorted top-4
__device__ __forceinline__ void ins4(float v, int idx,
                                     float& v0, int& i0, float& v1, int& i1,
                                     float& v2, int& i2, float& v3, int& i3) {
    bool b0 = (v > v0) | ((v == v0) & (idx < i0));
    bool b1 = (v > v1) | ((v == v1) & (idx < i1));
    bool b2 = (v > v2) | ((v == v2) & (idx < i2));
    bool b3 = (v > v3) | ((v == v3) & (idx < i3));
    float nv3 = b2 ? v2 : (b3 ? v : v3);
    int   ni3 = b2 ? i2 : (b3 ? idx : i3);
    float nv2 = b1 ? v1 : (b2 ? v : v2);
    int   ni2 = b1 ? i1 : (b2 ? idx : i2);
    float nv1 = b0 ? v0 : (b1 ? v : v1);
    int   ni1 = b0 ? i0 : (b1 ? idx : i1);
    float nv0 = b0 ? v : v0;
    int   ni0 = b0 ? idx : i0;
    v0 = nv0; i0 = ni0; v1 = nv1; i1 = ni1; v2 = nv2; i2 = ni2; v3 = nv3; i3 = ni3;
}

// ----------------- split: normalize + 2-way bf16 split, K-concatenated ------
// A' row = [h | h | m]   B' row = [h | m | h]   =>  A'.B' = hh + hm + mh
__global__ __launch_bounds__(256) void split2_kernel(
    const float* __restrict__ base, const float* __restrict__ real,
    ushort_t* __restrict__ Ap, ushort_t* __restrict__ Bp,
    float* __restrict__ inv) {
    int rid  = blockIdx.x * 4 + (threadIdx.x >> 6);
    int lane = threadIdx.x & 63;
    bool isA = rid < NB;
    int  row = isA ? rid : rid - NB;
    const float* src = isA ? base + (size_t)row * KDIM : real + (size_t)row * KDIM;
    float4 v = *(const float4*)(src + lane * 4);
    float ss = v.x * v.x + v.y * v.y + v.z * v.z + v.w * v.w;
    #pragma unroll
    for (int off = 32; off > 0; off >>= 1) ss += __shfl_xor(ss, off);
    float invn = 1.0f / fmaxf(sqrtf(ss), 1e-12f);

    float n[4] = {v.x * invn, v.y * invn, v.z * invn, v.w * invn};
    ushort_t h[4], m[4];
    #pragma unroll
    for (int e = 0; e < 4; ++e) {
        h[e] = f2bf(n[e]);
        m[e] = f2bf(n[e] - bf2f(h[e]));
    }
    ushort4 h4 = make_ushort4(h[0], h[1], h[2], h[3]);
    ushort4 m4 = make_ushort4(m[0], m[1], m[2], m[3]);
    ushort_t* d = (isA ? Ap : Bp) + (size_t)row * KP + lane * 4;
    *(ushort4*)(d)       = h4;
    *(ushort4*)(d + 256) = isA ? h4 : m4;
    *(ushort4*)(d + 512) = isA ? m4 : h4;
    if (lane == 0) inv[rid] = invn;
}

// --------------------- fused bf16 MFMA GEMM (K'=768) + per-block top-4 ------
// block 256 thr = 4 waves (2x2), tile 128x128, BK=64, 12 K-iterations.
// Epilogue: packed-key (value<<7 | col) u32 max-extract — cheap top-4.
__global__ __launch_bounds__(256) void mfma_topk_kernel(
    const ushort_t* __restrict__ Ap, const ushort_t* __restrict__ Bp,
    float* __restrict__ Pv, int* __restrict__ Pi) {
    __shared__ ushort_t sA[128 * 64];
    __shared__ ushort_t sB[128 * 64];

    const int tid  = threadIdx.x;
    const int lane = tid & 63;
    const int w    = tid >> 6;
    const int wr   = w >> 1, wc = w & 1;
    const int c    = lane & 15;       // frag col/row-in-16
    const int kg   = lane >> 4;       // frag k-group (0..3)
    const int lr8  = lane >> 3;       // staging: row within 8-row chunk
    const int ud   = lane & 7;        // staging: 16B slot within row (linear)

    // ---- bijective XCD supertile remap: 8192 blocks = 8 XCD x 16 st x 8x8 --
    int lin = blockIdx.y * 64 + blockIdx.x;     // gridDim = (64, 128)
    int xcd = lin & 7;
    int pos = lin >> 3;                          // 0..1023
    int gg  = xcd * 1024 + pos;                  // chunked per-XCD range
    int st  = gg >> 6, in8 = gg & 63;            // supertile id, pos within
    int my  = ((st >> 3) << 3) + (in8 >> 3);     // 0..127 row tile
    int nx  = ((st & 7) << 3) + (in8 & 7);       // 0..63  col tile
    const int m0 = my * 128;
    const int n0 = nx * 128;

    f32x4 acc[4][4];
    #pragma unroll
    for (int i = 0; i < 4; ++i)
        #pragma unroll
        for (int j = 0; j < 4; ++j) acc[i][j] = (f32x4){0.f, 0.f, 0.f, 0.f};

    #pragma unroll 1
    for (int kc = 0; kc < KP; kc += 64) {
        __syncthreads();   // LDS free (prev compute done)
        #pragma unroll
        for (int q = 0; q < 4; ++q) {
            int R = (w * 4 + q) * 8;           // 8-row chunk base
            gload16(Ap + (size_t)(m0 + R + lr8) * KP + kc + ud * 8,
                    (char*)sA + R * 128);
            gload16(Bp + (size_t)(n0 + R + lr8) * KP + kc + ud * 8,
                    (char*)sB + R * 128);
        }
        __syncthreads();   // staging complete
        #pragma unroll
        for (int kk = 0; kk < 2; ++kk) {
            short8 a[4], b[4];
            int u = kk * 4 + kg;
            #pragma unroll
            for (int i = 0; i < 4; ++i) {
                int ra = wr * 64 + i * 16 + c;
                a[i] = *(const short8*)(sA + ra * 64 + u * 8);
                int rb = wc * 64 + i * 16 + c;
                b[i] = *(const short8*)(sB + rb * 64 + u * 8);
            }
            #pragma unroll
            for (int i = 0; i < 4; ++i)
                #pragma unroll
                for (int j = 0; j < 4; ++j)
                    acc[i][j] = __builtin_amdgcn_mfma_f32_16x16x32_bf16(
                        a[i], b[j], acc[i][j], 0, 0, 0);
        }
    }

    // ---- per-row top-4 over this block's 128 cols (packed-key extract) ----
    // key = ((as_uint(v+2) - 0x3F800000) << 7) | col7 ; monotone in v,
    // unique per col; quantization <= 2.4e-7 (covered by exact rerank).
    __syncthreads();                       // done reading tiles; reuse LDS
    unsigned* mk = (unsigned*)sA;          // [128][2][4] keys
    #pragma unroll
    for (int i = 0; i < 4; ++i) {
        #pragma unroll
        for (int r = 0; r < 4; ++r) {
            unsigned k0 = ((__float_as_uint(acc[i][0][r] + 2.0f) - 0x3F800000u) << 7)
                          | (unsigned)(wc * 64 + 0 * 16 + c);
            unsigned k1 = ((__float_as_uint(acc[i][1][r] + 2.0f) - 0x3F800000u) << 7)
                          | (unsigned)(wc * 64 + 1 * 16 + c);
            unsigned k2 = ((__float_as_uint(acc[i][2][r] + 2.0f) - 0x3F800000u) << 7)
                          | (unsigned)(wc * 64 + 2 * 16 + c);
            unsigned k3 = ((__float_as_uint(acc[i][3][r] + 2.0f) - 0x3F800000u) << 7)
                          | (unsigned)(wc * 64 + 3 * 16 + c);
            unsigned top[4];
            #pragma unroll
            for (int p = 0; p < 4; ++p) {
                unsigned m01 = k0 > k1 ? k0 : k1;
                unsigned m23 = k2 > k3 ? k2 : k3;
                unsigned m   = m01 > m23 ? m01 : m23;
                #pragma unroll
                for (int mask = 1; mask <= 8; mask <<= 1) {
                    unsigned om = (unsigned)__shfl_xor((int)m, mask);
                    m = om > m ? om : m;
                }
                top[p] = m;
                k0 = (k0 == m) ? 0u : k0;
                k1 = (k1 == m) ? 0u : k1;
                k2 = (k2 == m) ? 0u : k2;
                k3 = (k3 == m) ? 0u : k3;
            }
            if (c == 0) {
                int row = wr * 64 + i * 16 + kg * 4 + r;
                *(uint4*)&mk[(row * 2 + wc) * 4] =
                    make_uint4(top[0], top[1], top[2], top[3]);
            }
        }
    }
    __syncthreads();
    if (tid < 128) {
        unsigned e[8];
        *(uint4*)&e[0] = *(const uint4*)&mk[tid * 8];
        *(uint4*)&e[4] = *(const uint4*)&mk[tid * 8 + 4];
        float vv[4]; int ii[4];
        #pragma unroll
        for (int p = 0; p < 4; ++p) {
            unsigned m = e[0];
            #pragma unroll
            for (int t = 1; t < 8; ++t) m = e[t] > m ? e[t] : m;
            vv[p] = __uint_as_float((m >> 7) + 0x3F800000u) - 2.0f;
            ii[p] = n0 + (int)(m & 127u);
            #pragma unroll
            for (int t = 0; t < 8; ++t) e[t] = (e[t] == m) ? 0u : e[t];
        }
        size_t o = (size_t)(m0 + tid) * 256 + nx * 4;   // [row][64 blocks][4]
        *(float4*)&Pv[o] = make_float4(vv[0], vv[1], vv[2], vv[3]);
        *(int4*)  &Pi[o] = make_int4(ii[0], ii[1], ii[2], ii[3]);
    }
}

// ---- stage-2: butterfly-merge 64x4 partials -> row top-4, exact f32 rerank -
// Rerank reproduces round-1's exact arithmetic: per element round(a*ia),
// round(b*ib), then a strict sequential fmaf chain in k order.
__global__ __launch_bounds__(256) void merge3_kernel(
    const float* __restrict__ Pv, const int* __restrict__ Pi,
    const float* __restrict__ base, const float* __restrict__ real,
    const float* __restrict__ inv, int* __restrict__ out) {
    int row  = blockIdx.x * 4 + (threadIdx.x >> 6);
    int lane = threadIdx.x & 63;
    float4 pv = *(const float4*)(Pv + (size_t)row * 256 + lane * 4);
    int4   pi = *(const int4*)  (Pi + (size_t)row * 256 + lane * 4);

    float v0 = -3.0e38f, v1 = -3.0e38f, v2 = -3.0e38f, v3 = -3.0e38f;
    int   i0 = 0x7fffffff, i1 = 0x7fffffff, i2 = 0x7fffffff, i3 = 0x7fffffff;
    ins4(pv.x, pi.x, v0, i0, v1, i1, v2, i2, v3, i3);
    ins4(pv.y, pi.y, v0, i0, v1, i1, v2, i2, v3, i3);
    ins4(pv.z, pi.z, v0, i0, v1, i1, v2, i2, v3, i3);
    ins4(pv.w, pi.w, v0, i0, v1, i1, v2, i2, v3, i3);
    #pragma unroll
    for (int mask = 1; mask <= 32; mask <<= 1) {
        float ov0 = __shfl_xor(v0, mask), ov1 = __shfl_xor(v1, mask),
              ov2 = __shfl_xor(v2, mask), ov3 = __shfl_xor(v3, mask);
        int   oi0 = __shfl_xor(i0, mask), oi1 = __shfl_xor(i1, mask),
              oi2 = __shfl_xor(i2, mask), oi3 = __shfl_xor(i3, mask);
        ins4(ov0, oi0, v0, i0, v1, i1, v2, i2, v3, i3);
        ins4(ov1, oi1, v0, i0, v1, i1, v2, i2, v3, i3);
        ins4(ov2, oi2, v0, i0, v1, i1, v2, i2, v3, i3);
        ins4(ov3, oi3, v0, i0, v1, i1, v2, i2, v3, i3);
    }
    // all lanes now hold the row's approx top-4 (identical across lanes)
    int cand = (lane == 0) ? i0 : (lane == 1) ? i1 : (lane == 2) ? i2 : i3;
    float s = 0.0f;
    if (lane < 4) {
        const float* a = base + (size_t)row  * KDIM;
        const float* b = real + (size_t)cand * KDIM;
        float ia = inv[row], ib = inv[NB + cand];
        #pragma unroll 4
        for (int k = 0; k < KDIM; k += 4) {
            float4 av = *(const float4*)(a + k);
            float4 bv = *(const float4*)(b + k);
            s = fmaf(av.x * ia, bv.x * ib, s);
            s = fmaf(av.y * ia, bv.y * ib, s);
            s = fmaf(av.z * ia, bv.z * ib, s);
            s = fmaf(av.w * ia, bv.w * ib, s);
        }
    }
    // gather the 4 exact scores, pick top-3
    float fv0 = -3.0e38f, fv1 = -3.0e38f, fv2 = -3.0e38f;
    int   fi0 = 0x7fffffff, fi1 = 0x7fffffff, fi2 = 0x7fffffff;
    #pragma unroll
    for (int l = 0; l < 4; ++l) {
        float sv = __shfl(s, l);
        int   si = __shfl(cand, l);
        ins3(sv, si, fv0, fi0, fv1, fi1, fv2, fi2);
    }
    if (lane == 0) {
        out[row * 3 + 0] = fi0;
        out[row * 3 + 1] = fi1;
        out[row * 3 + 2] = fi2;
    }
}

// ======================= fallback (round-1 f32 path) ========================
__global__ __launch_bounds__(256) void norm_kernel(const float* __restrict__ base,
                                                   const float* __restrict__ real,
                                                   float* __restrict__ inv) {
    int rid  = blockIdx.x * 4 + (threadIdx.x >> 6);
    int lane = threadIdx.x & 63;
    if (rid >= NB + NR) return;
    const float* src = (rid < NB) ? (base + (size_t)rid * KDIM)
                                  : (real + (size_t)(rid - NB) * KDIM);
    float4 v = *(const float4*)(src + lane * 4);
    float ss = v.x * v.x + v.y * v.y + v.z * v.z + v.w * v.w;
    #pragma unroll
    for (int off = 32; off > 0; off >>= 1) ss += __shfl_xor(ss, off);
    if (lane == 0) inv[rid] = 1.0f / fmaxf(sqrtf(ss), 1e-12f);
}

#define DOT(i, j, av, bv)                                                      \
    acc[i][j] = fmaf(av.x, bv.x, acc[i][j]);                                   \
    acc[i][j] = fmaf(av.y, bv.y, acc[i][j]);                                   \
    acc[i][j] = fmaf(av.z, bv.z, acc[i][j]);                                   \
    acc[i][j] = fmaf(av.w, bv.w, acc[i][j]);

__global__ __launch_bounds__(256) void simtopk_kernel(
    const float* __restrict__ A, const float* __restrict__ B,
    const float* __restrict__ invA, const float* __restrict__ invB,
    int* __restrict__ out) {
    __shared__ float sA[64 * 68];
    __shared__ float sB[64 * 68];
    const int tid = threadIdx.x;
    const int tx  = tid & 15;
    const int ty4 = (tid >> 4) << 2;
    const int m0  = blockIdx.x * 64;
    float t3v[4][3];
    int   t3i[4][3];
    #pragma unroll
    for (int i = 0; i < 4; ++i)
        #pragma unroll
        for (int s = 0; s < 3; ++s) { t3v[i][s] = -3.0e38f; t3i[i][s] = 0x7fffffff; }
    for (int nn0 = 0; nn0 < NR; nn0 += 64) {
        float acc[4][4] = {{0.f}};
        for (int kc = 0; kc < KDIM; kc += 64) {
            __syncthreads();
            #pragma unroll
            for (int p = 0; p < 4; ++p) {
                int f = tid + (p << 8), row = f >> 4, c4 = (f & 15) << 2;
                float4 va = *(const float4*)(A + (size_t)(m0 + row) * KDIM + kc + c4);
                float  sa = invA[m0 + row];
                va.x *= sa; va.y *= sa; va.z *= sa; va.w *= sa;
                *(float4*)&sA[row * 68 + c4] = va;
                float4 vb = *(const float4*)(B + (size_t)(nn0 + row) * KDIM + kc + c4);
                float  sb = invB[nn0 + row];
                vb.x *= sb; vb.y *= sb; vb.z *= sb; vb.w *= sb;
                *(float4*)&sB[row * 68 + c4] = vb;
            }
            __syncthreads();
            #pragma unroll
            for (int k = 0; k < 64; k += 4) {
                float4 a0 = *(const float4*)&sA[(ty4 + 0) * 68 + k];
                float4 a1 = *(const float4*)&sA[(ty4 + 1) * 68 + k];
                float4 a2 = *(const float4*)&sA[(ty4 + 2) * 68 + k];
                float4 a3 = *(const float4*)&sA[(ty4 + 3) * 68 + k];
                float4 b0 = *(const float4*)&sB[(tx +  0) * 68 + k];
                float4 b1 = *(const float4*)&sB[(tx + 16) * 68 + k];
                float4 b2 = *(const float4*)&sB[(tx + 32) * 68 + k];
                float4 b3 = *(const float4*)&sB[(tx + 48) * 68 + k];
                DOT(0,0,a0,b0) DOT(0,1,a0,b1) DOT(0,2,a0,b2) DOT(0,3,a0,b3)
                DOT(1,0,a1,b0) DOT(1,1,a1,b1) DOT(1,2,a1,b2) DOT(1,3,a1,b3)
                DOT(2,0,a2,b0) DOT(2,1,a2,b1) DOT(2,2,a2,b2) DOT(2,3,a2,b3)
                DOT(3,0,a3,b0) DOT(3,1,a3,b1) DOT(3,2,a3,b2) DOT(3,3,a3,b3)
            }
        }
        #pragma unroll
        for (int i = 0; i < 4; ++i)
            #pragma unroll
            for (int j = 0; j < 4; ++j)
                ins3(acc[i][j], nn0 + tx + 16 * j,
                     t3v[i][0], t3i[i][0], t3v[i][1], t3i[i][1], t3v[i][2], t3i[i][2]);
    }
    __syncthreads();
    float* mv = sA;
    int*   mi = (int*)sB;
    #pragma unroll
    for (int i = 0; i < 4; ++i)
        #pragma unroll
        for (int s = 0; s < 3; ++s) {
            mv[(ty4 + i) * 48 + tx * 3 + s] = t3v[i][s];
            mi[(ty4 + i) * 48 + tx * 3 + s] = t3i[i][s];
        }
    __syncthreads();
    if (tid < 64) {
        float v0 = -3.0e38f, v1 = -3.0e38f, v2 = -3.0e38f;
        int   i0 = 0x7fffffff, i1 = 0x7fffffff, i2 = 0x7fffffff;
        for (int e = 0; e < 48; ++e)
            ins3(mv[tid * 48 + e], mi[tid * 48 + e], v0, i0, v1, i1, v2, i2);
        out[(m0 + tid) * 3 + 0] = i0;
        out[(m0 + tid) * 3 + 1] = i1;
        out[(m0 + tid) * 3 + 2] = i2;
    }
}

// ============================================================== launcher ====
extern "C" void kernel_launch(void* const* d_in, const int* in_sizes, int n_in,
                              void* d_out, int out_size, void* d_ws, size_t ws_size,
                              hipStream_t stream) {
    const float* base = (const float*)d_in[0];
    const float* real = (const float*)d_in[1];
    int* out = (int*)d_out;

    const size_t szAp  = (size_t)NB * KP * 2;        // 25.2 MB
    const size_t szBp  = (size_t)NR * KP * 2;        // 12.6 MB
    const size_t szPv  = (size_t)NB * 256 * 4;       // 16.8 MB
    const size_t szInv = (size_t)(NB + NR) * 4;      // 0.1 MB
    const size_t need  = szAp + szBp + 2 * szPv + szInv;

    if (ws_size >= need) {
        char* p = (char*)d_ws;
        ushort_t* Ap  = (ushort_t*)(p);
        ushort_t* Bp  = (ushort_t*)(p + szAp);
        float*    Pv  = (float*)   (p + szAp + szBp);
        int*      Pi  = (int*)     (p + szAp + szBp + szPv);
        float*    inv = (float*)   (p + szAp + szBp + 2 * szPv);

        hipLaunchKernelGGL(split2_kernel, dim3((NB + NR) / 4), dim3(256), 0, stream,
                           base, real, Ap, Bp, inv);
        hipLaunchKernelGGL(mfma_topk_kernel, dim3(NR / 128, NB / 128), dim3(256), 0,
                           stream, Ap, Bp, Pv, Pi);
        hipLaunchKernelGGL(merge3_kernel, dim3(NB / 4), dim3(256), 0, stream,
                           Pv, Pi, base, real, inv, out);
    } else {
        float* inv = (float*)d_ws;
        hipLaunchKernelGGL(norm_kernel, dim3((NB + NR) / 4), dim3(256), 0, stream,
                           base, real, inv);
        hipLaunchKernelGGL(simtopk_kernel, dim3(NB / 64), dim3(256), 0, stream,
                           base, real, inv, inv + NB, out);
    }
}

// Round 7
// 373.395 us; speedup vs baseline: 2.5145x; 1.4569x over previous
//
#include <hip/hip_runtime.h>

#define KDIM 256
#define NB 16384
#define NR 8192

typedef unsigned short ushort_t;
typedef __attribute__((ext_vector_type(8))) short short8;
typedef __attribute__((ext_vector_type(4))) float f32x4;

// ---------------------------------------------------------------- helpers ---
__device__ __forceinline__ ushort_t f2bf(float f) {          // RNE f32->bf16
    unsigned u = __float_as_uint(f);
    unsigned r = (u + 0x7fffu + ((u >> 16) & 1u)) >> 16;
    return (ushort_t)r;
}
__device__ __forceinline__ void gload16(const void* g, void* l) {
    __builtin_amdgcn_global_load_lds(
        (const __attribute__((address_space(1))) void*)g,
        (__attribute__((address_space(3))) void*)l, 16, 0, 0);
}
// branchless insert into sorted top-3 (v desc, idx asc on ties)
__device__ __forceinline__ void ins3(float v, int idx,
                                     float& v0, int& i0, float& v1, int& i1,
                                     float& v2, int& i2) {
    bool b0 = (v > v0) | ((v == v0) & (idx < i0));
    bool b1 = (v > v1) | ((v == v1) & (idx < i1));
    bool b2 = (v > v2) | ((v == v2) & (idx < i2));
    float nv2 = b1 ? v1 : (b2 ? v : v2);
    int   ni2 = b1 ? i1 : (b2 ? idx : i2);
    float nv1 = b0 ? v0 : (b1 ? v : v1);
    int   ni1 = b0 ? i0 : (b1 ? idx : i1);
    float nv0 = b0 ? v : v0;
    int   ni0 = b0 ? idx : i0;
    v0 = nv0; i0 = ni0; v1 = nv1; i1 = ni1; v2 = nv2; i2 = ni2;
}
// branchless insert into sorted top-4
__device__ __forceinline__ void ins4(float v, int idx,
                                     float& v0, int& i0, float& v1, int& i1,
                                     float& v2, int& i2, float& v3, int& i3) {
    bool b0 = (v > v0) | ((v == v0) & (idx < i0));
    bool b1 = (v > v1) | ((v == v1) & (idx < i1));
    bool b2 = (v > v2) | ((v == v2) & (idx < i2));
    bool b3 = (v > v3) | ((v == v3) & (idx < i3));
    float nv3 = b2 ? v2 : (b3 ? v : v3);
    int   ni3 = b2 ? i2 : (b3 ? idx : i3);
    float nv2 = b1 ? v1 : (b2 ? v : v2);
    int   ni2 = b1 ? i1 : (b2 ? idx : i2);
    float nv1 = b0 ? v0 : (b1 ? v : v1);
    int   ni1 = b0 ? i0 : (b1 ? idx : i1);
    float nv0 = b0 ? v : v0;
    int   ni0 = b0 ? idx : i0;
    v0 = nv0; i0 = ni0; v1 = nv1; i1 = ni1; v2 = nv2; i2 = ni2; v3 = nv3; i3 = ni3;
}

// ----------------- split: normalize + single bf16 (h) conversion ------------
__global__ __launch_bounds__(256) void split_h_kernel(
    const float* __restrict__ base, const float* __restrict__ real,
    ushort_t* __restrict__ Ah, ushort_t* __restrict__ Bh,
    float* __restrict__ inv) {
    int rid  = blockIdx.x * 4 + (threadIdx.x >> 6);
    int lane = threadIdx.x & 63;
    bool isA = rid < NB;
    int  row = isA ? rid : rid - NB;
    const float* src = isA ? base + (size_t)row * KDIM : real + (size_t)row * KDIM;
    float4 v = *(const float4*)(src + lane * 4);
    float ss = v.x * v.x + v.y * v.y + v.z * v.z + v.w * v.w;
    #pragma unroll
    for (int off = 32; off > 0; off >>= 1) ss += __shfl_xor(ss, off);
    float invn = 1.0f / fmaxf(sqrtf(ss), 1e-12f);

    ushort4 h4 = make_ushort4(f2bf(v.x * invn), f2bf(v.y * invn),
                              f2bf(v.z * invn), f2bf(v.w * invn));
    *(ushort4*)((isA ? Ah : Bh) + (size_t)row * KDIM + lane * 4) = h4;
    if (lane == 0) inv[rid] = invn;
}

// --------------------- bf16 MFMA GEMM (K=256) + per-block top-4 -------------
// block 256 thr = 4 waves (2x2), tile 128x128, BK=64, 4 K-iterations.
// Epilogue: packed-key (value<<7 | col) u32 max-extract (R6-proven).
__global__ __launch_bounds__(256) void mfma_topk_kernel(
    const ushort_t* __restrict__ Ah, const ushort_t* __restrict__ Bh,
    float* __restrict__ Pv, int* __restrict__ Pi) {
    __shared__ ushort_t sA[128 * 64];
    __shared__ ushort_t sB[128 * 64];

    const int tid  = threadIdx.x;
    const int lane = tid & 63;
    const int w    = tid >> 6;
    const int wr   = w >> 1, wc = w & 1;
    const int c    = lane & 15;       // frag col/row-in-16
    const int kg   = lane >> 4;       // frag k-group (0..3)
    const int lr8  = lane >> 3;       // staging: row within 8-row chunk
    const int ud   = lane & 7;        // staging: 16B slot within row (linear)

    // ---- bijective XCD supertile remap: 8192 blocks = 8 XCD x 16 st x 8x8 --
    int lin = blockIdx.y * 64 + blockIdx.x;     // gridDim = (64, 128)
    int xcd = lin & 7;
    int pos = lin >> 3;                          // 0..1023
    int gg  = xcd * 1024 + pos;                  // chunked per-XCD range
    int st  = gg >> 6, in8 = gg & 63;            // supertile id, pos within
    int my  = ((st >> 3) << 3) + (in8 >> 3);     // 0..127 row tile
    int nx  = ((st & 7) << 3) + (in8 & 7);       // 0..63  col tile
    const int m0 = my * 128;
    const int n0 = nx * 128;

    f32x4 acc[4][4];
    #pragma unroll
    for (int i = 0; i < 4; ++i)
        #pragma unroll
        for (int j = 0; j < 4; ++j) acc[i][j] = (f32x4){0.f, 0.f, 0.f, 0.f};

    #pragma unroll 1
    for (int kc = 0; kc < KDIM; kc += 64) {
        __syncthreads();   // LDS free (prev compute done)
        #pragma unroll
        for (int q = 0; q < 4; ++q) {
            int R = (w * 4 + q) * 8;           // 8-row chunk base
            gload16(Ah + (size_t)(m0 + R + lr8) * KDIM + kc + ud * 8,
                    (char*)sA + R * 128);
            gload16(Bh + (size_t)(n0 + R + lr8) * KDIM + kc + ud * 8,
                    (char*)sB + R * 128);
        }
        __syncthreads();   // staging complete
        #pragma unroll
        for (int kk = 0; kk < 2; ++kk) {
            short8 a[4], b[4];
            int u = kk * 4 + kg;
            #pragma unroll
            for (int i = 0; i < 4; ++i) {
                int ra = wr * 64 + i * 16 + c;
                a[i] = *(const short8*)(sA + ra * 64 + u * 8);
                int rb = wc * 64 + i * 16 + c;
                b[i] = *(const short8*)(sB + rb * 64 + u * 8);
            }
            #pragma unroll
            for (int i = 0; i < 4; ++i)
                #pragma unroll
                for (int j = 0; j < 4; ++j)
                    acc[i][j] = __builtin_amdgcn_mfma_f32_16x16x32_bf16(
                        a[i], b[j], acc[i][j], 0, 0, 0);
        }
    }

    // ---- per-row top-4 over this block's 128 cols (packed-key extract) ----
    // key = ((as_uint(v+2) - 0x3F800000) << 7) | col7 ; monotone in v,
    // unique per col; quantization <= 2.4e-7 (covered by exact rerank).
    __syncthreads();                       // done reading tiles; reuse LDS
    unsigned* mk = (unsigned*)sA;          // [128][2][4] keys
    #pragma unroll
    for (int i = 0; i < 4; ++i) {
        #pragma unroll
        for (int r = 0; r < 4; ++r) {
            unsigned k0 = ((__float_as_uint(acc[i][0][r] + 2.0f) - 0x3F800000u) << 7)
                          | (unsigned)(wc * 64 + 0 * 16 + c);
            unsigned k1 = ((__float_as_uint(acc[i][1][r] + 2.0f) - 0x3F800000u) << 7)
                          | (unsigned)(wc * 64 + 1 * 16 + c);
            unsigned k2 = ((__float_as_uint(acc[i][2][r] + 2.0f) - 0x3F800000u) << 7)
                          | (unsigned)(wc * 64 + 2 * 16 + c);
            unsigned k3 = ((__float_as_uint(acc[i][3][r] + 2.0f) - 0x3F800000u) << 7)
                          | (unsigned)(wc * 64 + 3 * 16 + c);
            unsigned top[4];
            #pragma unroll
            for (int p = 0; p < 4; ++p) {
                unsigned m01 = k0 > k1 ? k0 : k1;
                unsigned m23 = k2 > k3 ? k2 : k3;
                unsigned m   = m01 > m23 ? m01 : m23;
                #pragma unroll
                for (int mask = 1; mask <= 8; mask <<= 1) {
                    unsigned om = (unsigned)__shfl_xor((int)m, mask);
                    m = om > m ? om : m;
                }
                top[p] = m;
                k0 = (k0 == m) ? 0u : k0;
                k1 = (k1 == m) ? 0u : k1;
                k2 = (k2 == m) ? 0u : k2;
                k3 = (k3 == m) ? 0u : k3;
            }
            if (c == 0) {
                int row = wr * 64 + i * 16 + kg * 4 + r;
                *(uint4*)&mk[(row * 2 + wc) * 4] =
                    make_uint4(top[0], top[1], top[2], top[3]);
            }
        }
    }
    __syncthreads();
    if (tid < 128) {
        unsigned e[8];
        *(uint4*)&e[0] = *(const uint4*)&mk[tid * 8];
        *(uint4*)&e[4] = *(const uint4*)&mk[tid * 8 + 4];
        float vv[4]; int ii[4];
        #pragma unroll
        for (int p = 0; p < 4; ++p) {
            unsigned m = e[0];
            #pragma unroll
            for (int t = 1; t < 8; ++t) m = e[t] > m ? e[t] : m;
            vv[p] = __uint_as_float((m >> 7) + 0x3F800000u) - 2.0f;
            ii[p] = n0 + (int)(m & 127u);
            #pragma unroll
            for (int t = 0; t < 8; ++t) e[t] = (e[t] == m) ? 0u : e[t];
        }
        size_t o = (size_t)(m0 + tid) * 256 + nx * 4;   // [row][64 blocks][4]
        *(float4*)&Pv[o] = make_float4(vv[0], vv[1], vv[2], vv[3]);
        *(int4*)  &Pi[o] = make_int4(ii[0], ii[1], ii[2], ii[3]);
    }
}

// ---- stage-2: butterfly-merge -> global top-8, exact f32 rerank of 8 -------
// Rerank reproduces round-1's exact arithmetic: per element round(a*ia),
// round(b*ib), then a strict sequential fmaf chain in k order.
__global__ __launch_bounds__(256) void merge8_kernel(
    const float* __restrict__ Pv, const int* __restrict__ Pi,
    const float* __restrict__ base, const float* __restrict__ real,
    const float* __restrict__ inv, int* __restrict__ out) {
    int row  = blockIdx.x * 4 + (threadIdx.x >> 6);
    int lane = threadIdx.x & 63;
    float4 pv = *(const float4*)(Pv + (size_t)row * 256 + lane * 4);
    int4   pi = *(const int4*)  (Pi + (size_t)row * 256 + lane * 4);
    float lv[4] = {pv.x, pv.y, pv.z, pv.w};
    int   li[4] = {pi.x, pi.y, pi.z, pi.w};

    int topi[8];
    #pragma unroll
    for (int half = 0; half < 2; ++half) {
        float v0 = -3.0e38f, v1 = -3.0e38f, v2 = -3.0e38f, v3 = -3.0e38f;
        int   i0 = 0x7fffffff, i1 = 0x7fffffff, i2 = 0x7fffffff, i3 = 0x7fffffff;
        #pragma unroll
        for (int e = 0; e < 4; ++e)
            ins4(lv[e], li[e], v0, i0, v1, i1, v2, i2, v3, i3);
        #pragma unroll
        for (int mask = 1; mask <= 32; mask <<= 1) {
            float ov0 = __shfl_xor(v0, mask), ov1 = __shfl_xor(v1, mask),
                  ov2 = __shfl_xor(v2, mask), ov3 = __shfl_xor(v3, mask);
            int   oi0 = __shfl_xor(i0, mask), oi1 = __shfl_xor(i1, mask),
                  oi2 = __shfl_xor(i2, mask), oi3 = __shfl_xor(i3, mask);
            ins4(ov0, oi0, v0, i0, v1, i1, v2, i2, v3, i3);
            ins4(ov1, oi1, v0, i0, v1, i1, v2, i2, v3, i3);
            ins4(ov2, oi2, v0, i0, v1, i1, v2, i2, v3, i3);
            ins4(ov3, oi3, v0, i0, v1, i1, v2, i2, v3, i3);
        }
        topi[half * 4 + 0] = i0; topi[half * 4 + 1] = i1;
        topi[half * 4 + 2] = i2; topi[half * 4 + 3] = i3;
        if (half == 0) {
            #pragma unroll
            for (int e = 0; e < 4; ++e) {
                bool hit = (li[e] == i0) | (li[e] == i1) |
                           (li[e] == i2) | (li[e] == i3);
                lv[e] = hit ? -3.0e38f : lv[e];
            }
        }
    }

    // exact f32 re-rank of the 8 candidates (one per lane 0..7)
    int cand = topi[0];
    #pragma unroll
    for (int l = 1; l < 8; ++l) cand = (lane == l) ? topi[l] : cand;
    float s = 0.0f;
    if (lane < 8) {
        const float* a = base + (size_t)row  * KDIM;
        const float* b = real + (size_t)cand * KDIM;
        float ia = inv[row], ib = inv[NB + cand];
        #pragma unroll 4
        for (int k = 0; k < KDIM; k += 4) {
            float4 av = *(const float4*)(a + k);
            float4 bv = *(const float4*)(b + k);
            s = fmaf(av.x * ia, bv.x * ib, s);
            s = fmaf(av.y * ia, bv.y * ib, s);
            s = fmaf(av.z * ia, bv.z * ib, s);
            s = fmaf(av.w * ia, bv.w * ib, s);
        }
    }
    float fv0 = -3.0e38f, fv1 = -3.0e38f, fv2 = -3.0e38f;
    int   fi0 = 0x7fffffff, fi1 = 0x7fffffff, fi2 = 0x7fffffff;
    #pragma unroll
    for (int l = 0; l < 8; ++l) {
        float sv = __shfl(s, l);
        int   si = __shfl(cand, l);
        ins3(sv, si, fv0, fi0, fv1, fi1, fv2, fi2);
    }
    if (lane == 0) {
        out[row * 3 + 0] = fi0;
        out[row * 3 + 1] = fi1;
        out[row * 3 + 2] = fi2;
    }
}

// ======================= fallback (round-1 f32 path) ========================
__global__ __launch_bounds__(256) void norm_kernel(const float* __restrict__ base,
                                                   const float* __restrict__ real,
                                                   float* __restrict__ inv) {
    int rid  = blockIdx.x * 4 + (threadIdx.x >> 6);
    int lane = threadIdx.x & 63;
    if (rid >= NB + NR) return;
    const float* src = (rid < NB) ? (base + (size_t)rid * KDIM)
                                  : (real + (size_t)(rid - NB) * KDIM);
    float4 v = *(const float4*)(src + lane * 4);
    float ss = v.x * v.x + v.y * v.y + v.z * v.z + v.w * v.w;
    #pragma unroll
    for (int off = 32; off > 0; off >>= 1) ss += __shfl_xor(ss, off);
    if (lane == 0) inv[rid] = 1.0f / fmaxf(sqrtf(ss), 1e-12f);
}

#define DOT(i, j, av, bv)                                                      \
    acc[i][j] = fmaf(av.x, bv.x, acc[i][j]);                                   \
    acc[i][j] = fmaf(av.y, bv.y, acc[i][j]);                                   \
    acc[i][j] = fmaf(av.z, bv.z, acc[i][j]);                                   \
    acc[i][j] = fmaf(av.w, bv.w, acc[i][j]);

__global__ __launch_bounds__(256) void simtopk_kernel(
    const float* __restrict__ A, const float* __restrict__ B,
    const float* __restrict__ invA, const float* __restrict__ invB,
    int* __restrict__ out) {
    __shared__ float sA[64 * 68];
    __shared__ float sB[64 * 68];
    const int tid = threadIdx.x;
    const int tx  = tid & 15;
    const int ty4 = (tid >> 4) << 2;
    const int m0  = blockIdx.x * 64;
    float t3v[4][3];
    int   t3i[4][3];
    #pragma unroll
    for (int i = 0; i < 4; ++i)
        #pragma unroll
        for (int s = 0; s < 3; ++s) { t3v[i][s] = -3.0e38f; t3i[i][s] = 0x7fffffff; }
    for (int nn0 = 0; nn0 < NR; nn0 += 64) {
        float acc[4][4] = {{0.f}};
        for (int kc = 0; kc < KDIM; kc += 64) {
            __syncthreads();
            #pragma unroll
            for (int p = 0; p < 4; ++p) {
                int f = tid + (p << 8), row = f >> 4, c4 = (f & 15) << 2;
                float4 va = *(const float4*)(A + (size_t)(m0 + row) * KDIM + kc + c4);
                float  sa = invA[m0 + row];
                va.x *= sa; va.y *= sa; va.z *= sa; va.w *= sa;
                *(float4*)&sA[row * 68 + c4] = va;
                float4 vb = *(const float4*)(B + (size_t)(nn0 + row) * KDIM + kc + c4);
                float  sb = invB[nn0 + row];
                vb.x *= sb; vb.y *= sb; vb.z *= sb; vb.w *= sb;
                *(float4*)&sB[row * 68 + c4] = vb;
            }
            __syncthreads();
            #pragma unroll
            for (int k = 0; k < 64; k += 4) {
                float4 a0 = *(const float4*)&sA[(ty4 + 0) * 68 + k];
                float4 a1 = *(const float4*)&sA[(ty4 + 1) * 68 + k];
                float4 a2 = *(const float4*)&sA[(ty4 + 2) * 68 + k];
                float4 a3 = *(const float4*)&sA[(ty4 + 3) * 68 + k];
                float4 b0 = *(const float4*)&sB[(tx +  0) * 68 + k];
                float4 b1 = *(const float4*)&sB[(tx + 16) * 68 + k];
                float4 b2 = *(const float4*)&sB[(tx + 32) * 68 + k];
                float4 b3 = *(const float4*)&sB[(tx + 48) * 68 + k];
                DOT(0,0,a0,b0) DOT(0,1,a0,b1) DOT(0,2,a0,b2) DOT(0,3,a0,b3)
                DOT(1,0,a1,b0) DOT(1,1,a1,b1) DOT(1,2,a1,b2) DOT(1,3,a1,b3)
                DOT(2,0,a2,b0) DOT(2,1,a2,b1) DOT(2,2,a2,b2) DOT(2,3,a2,b3)
                DOT(3,0,a3,b0) DOT(3,1,a3,b1) DOT(3,2,a3,b2) DOT(3,3,a3,b3)
            }
        }
        #pragma unroll
        for (int i = 0; i < 4; ++i)
            #pragma unroll
            for (int j = 0; j < 4; ++j)
                ins3(acc[i][j], nn0 + tx + 16 * j,
                     t3v[i][0], t3i[i][0], t3v[i][1], t3i[i][1], t3v[i][2], t3i[i][2]);
    }
    __syncthreads();
    float* mv = sA;
    int*   mi = (int*)sB;
    #pragma unroll
    for (int i = 0; i < 4; ++i)
        #pragma unroll
        for (int s = 0; s < 3; ++s) {
            mv[(ty4 + i) * 48 + tx * 3 + s] = t3v[i][s];
            mi[(ty4 + i) * 48 + tx * 3 + s] = t3i[i][s];
        }
    __syncthreads();
    if (tid < 64) {
        float v0 = -3.0e38f, v1 = -3.0e38f, v2 = -3.0e38f;
        int   i0 = 0x7fffffff, i1 = 0x7fffffff, i2 = 0x7fffffff;
        for (int e = 0; e < 48; ++e)
            ins3(mv[tid * 48 + e], mi[tid * 48 + e], v0, i0, v1, i1, v2, i2);
        out[(m0 + tid) * 3 + 0] = i0;
        out[(m0 + tid) * 3 + 1] = i1;
        out[(m0 + tid) * 3 + 2] = i2;
    }
}

// ============================================================== launcher ====
extern "C" void kernel_launch(void* const* d_in, const int* in_sizes, int n_in,
                              void* d_out, int out_size, void* d_ws, size_t ws_size,
                              hipStream_t stream) {
    const float* base = (const float*)d_in[0];
    const float* real = (const float*)d_in[1];
    int* out = (int*)d_out;

    const size_t szAh  = (size_t)NB * KDIM * 2;      // 8.4 MB
    const size_t szBh  = (size_t)NR * KDIM * 2;      // 4.2 MB
    const size_t szPv  = (size_t)NB * 256 * 4;       // 16.8 MB
    const size_t szInv = (size_t)(NB + NR) * 4;      // 0.1 MB
    const size_t need  = szAh + szBh + 2 * szPv + szInv;

    if (ws_size >= need) {
        char* p = (char*)d_ws;
        ushort_t* Ah  = (ushort_t*)(p);
        ushort_t* Bh  = (ushort_t*)(p + szAh);
        float*    Pv  = (float*)   (p + szAh + szBh);
        int*      Pi  = (int*)     (p + szAh + szBh + szPv);
        float*    inv = (float*)   (p + szAh + szBh + 2 * szPv);

        hipLaunchKernelGGL(split_h_kernel, dim3((NB + NR) / 4), dim3(256), 0, stream,
                           base, real, Ah, Bh, inv);
        hipLaunchKernelGGL(mfma_topk_kernel, dim3(NR / 128, NB / 128), dim3(256), 0,
                           stream, Ah, Bh, Pv, Pi);
        hipLaunchKernelGGL(merge8_kernel, dim3(NB / 4), dim3(256), 0, stream,
                           Pv, Pi, base, real, inv, out);
    } else {
        float* inv = (float*)d_ws;
        hipLaunchKernelGGL(norm_kernel, dim3((NB + NR) / 4), dim3(256), 0, stream,
                           base, real, inv);
        hipLaunchKernelGGL(simtopk_kernel, dim3(NB / 64), dim3(256), 0, stream,
                           base, real, inv, inv + NB, out);
    }
}

// Round 8
// 257.729 us; speedup vs baseline: 3.6429x; 1.4488x over previous
//
#include <hip/hip_runtime.h>

#define KDIM 256
#define NB 16384
#define NR 8192

typedef unsigned short ushort_t;
typedef __attribute__((ext_vector_type(8))) short short8;
typedef __attribute__((ext_vector_type(4))) float f32x4;

// ---------------------------------------------------------------- helpers ---
__device__ __forceinline__ ushort_t f2bf(float f) {          // RNE f32->bf16
    unsigned u = __float_as_uint(f);
    unsigned r = (u + 0x7fffu + ((u >> 16) & 1u)) >> 16;
    return (ushort_t)r;
}
__device__ __forceinline__ void gload16(const void* g, void* l) {
    __builtin_amdgcn_global_load_lds(
        (const __attribute__((address_space(1))) void*)g,
        (__attribute__((address_space(3))) void*)l, 16, 0, 0);
}
// 16-lane all-reduce max on the VALU pipe: v_max through DPP row rotations
// (row_ror:1,2,4,8 — each DPP "row" is 16 lanes; shifts compose to full max)
__device__ __forceinline__ unsigned rowmax16(unsigned m) {
    unsigned t;
    t = (unsigned)__builtin_amdgcn_update_dpp(0, (int)m, 0x121, 0xf, 0xf, true);
    m = t > m ? t : m;
    t = (unsigned)__builtin_amdgcn_update_dpp(0, (int)m, 0x122, 0xf, 0xf, true);
    m = t > m ? t : m;
    t = (unsigned)__builtin_amdgcn_update_dpp(0, (int)m, 0x124, 0xf, 0xf, true);
    m = t > m ? t : m;
    t = (unsigned)__builtin_amdgcn_update_dpp(0, (int)m, 0x128, 0xf, 0xf, true);
    m = t > m ? t : m;
    return m;
}
// branchless insert into sorted top-3 (v desc, idx asc on ties)
__device__ __forceinline__ void ins3(float v, int idx,
                                     float& v0, int& i0, float& v1, int& i1,
                                     float& v2, int& i2) {
    bool b0 = (v > v0) | ((v == v0) & (idx < i0));
    bool b1 = (v > v1) | ((v == v1) & (idx < i1));
    bool b2 = (v > v2) | ((v == v2) & (idx < i2));
    float nv2 = b1 ? v1 : (b2 ? v : v2);
    int   ni2 = b1 ? i1 : (b2 ? idx : i2);
    float nv1 = b0 ? v0 : (b1 ? v : v1);
    int   ni1 = b0 ? i0 : (b1 ? idx : i1);
    float nv0 = b0 ? v : v0;
    int   ni0 = b0 ? idx : i0;
    v0 = nv0; i0 = ni0; v1 = nv1; i1 = ni1; v2 = nv2; i2 = ni2;
}
// branchless insert into sorted top-4
__device__ __forceinline__ void ins4(float v, int idx,
                                     float& v0, int& i0, float& v1, int& i1,
                                     float& v2, int& i2, float& v3, int& i3) {
    bool b0 = (v > v0) | ((v == v0) & (idx < i0));
    bool b1 = (v > v1) | ((v == v1) & (idx < i1));
    bool b2 = (v > v2) | ((v == v2) & (idx < i2));
    bool b3 = (v > v3) | ((v == v3) & (idx < i3));
    float nv3 = b2 ? v2 : (b3 ? v : v3);
    int   ni3 = b2 ? i2 : (b3 ? idx : i3);
    float nv2 = b1 ? v1 : (b2 ? v : v2);
    int   ni2 = b1 ? i1 : (b2 ? idx : i2);
    float nv1 = b0 ? v0 : (b1 ? v : v1);
    int   ni1 = b0 ? i0 : (b1 ? idx : i1);
    float nv0 = b0 ? v : v0;
    int   ni0 = b0 ? idx : i0;
    v0 = nv0; i0 = ni0; v1 = nv1; i1 = ni1; v2 = nv2; i2 = ni2; v3 = nv3; i3 = ni3;
}

// ----------------- split: normalize + single bf16 (h) conversion ------------
__global__ __launch_bounds__(256) void split_h_kernel(
    const float* __restrict__ base, const float* __restrict__ real,
    ushort_t* __restrict__ Ah, ushort_t* __restrict__ Bh,
    float* __restrict__ inv) {
    int rid  = blockIdx.x * 4 + (threadIdx.x >> 6);
    int lane = threadIdx.x & 63;
    bool isA = rid < NB;
    int  row = isA ? rid : rid - NB;
    const float* src = isA ? base + (size_t)row * KDIM : real + (size_t)row * KDIM;
    float4 v = *(const float4*)(src + lane * 4);
    float ss = v.x * v.x + v.y * v.y + v.z * v.z + v.w * v.w;
    #pragma unroll
    for (int off = 32; off > 0; off >>= 1) ss += __shfl_xor(ss, off);
    float invn = 1.0f / fmaxf(sqrtf(ss), 1e-12f);

    ushort4 h4 = make_ushort4(f2bf(v.x * invn), f2bf(v.y * invn),
                              f2bf(v.z * invn), f2bf(v.w * invn));
    *(ushort4*)((isA ? Ah : Bh) + (size_t)row * KDIM + lane * 4) = h4;
    if (lane == 0) inv[rid] = invn;
}

// --------------------- bf16 MFMA GEMM (K=256) + per-block top-4 -------------
// block 256 thr = 4 waves (2x2), tile 128x128, BK=64, 4 K-iterations.
// Epilogue: packed-key (value<<7 | col) u32 max-extract, DPP row-max.
__global__ __launch_bounds__(256) void mfma_topk_kernel(
    const ushort_t* __restrict__ Ah, const ushort_t* __restrict__ Bh,
    float* __restrict__ Pv, int* __restrict__ Pi) {
    __shared__ ushort_t sA[128 * 64];
    __shared__ ushort_t sB[128 * 64];

    const int tid  = threadIdx.x;
    const int lane = tid & 63;
    const int w    = tid >> 6;
    const int wr   = w >> 1, wc = w & 1;
    const int c    = lane & 15;       // frag col/row-in-16
    const int kg   = lane >> 4;       // frag k-group (0..3)
    const int lr8  = lane >> 3;       // staging: row within 8-row chunk
    const int ud   = lane & 7;        // staging: 16B slot within row (linear)

    // ---- bijective XCD supertile remap: 8192 blocks = 8 XCD x 16 st x 8x8 --
    int lin = blockIdx.y * 64 + blockIdx.x;     // gridDim = (64, 128)
    int xcd = lin & 7;
    int pos = lin >> 3;                          // 0..1023
    int gg  = xcd * 1024 + pos;                  // chunked per-XCD range
    int st  = gg >> 6, in8 = gg & 63;            // supertile id, pos within
    int my  = ((st >> 3) << 3) + (in8 >> 3);     // 0..127 row tile
    int nx  = ((st & 7) << 3) + (in8 & 7);       // 0..63  col tile
    const int m0 = my * 128;
    const int n0 = nx * 128;

    f32x4 acc[4][4];
    #pragma unroll
    for (int i = 0; i < 4; ++i)
        #pragma unroll
        for (int j = 0; j < 4; ++j) acc[i][j] = (f32x4){0.f, 0.f, 0.f, 0.f};

    #pragma unroll 1
    for (int kc = 0; kc < KDIM; kc += 64) {
        __syncthreads();   // LDS free (prev compute done)
        #pragma unroll
        for (int q = 0; q < 4; ++q) {
            int R = (w * 4 + q) * 8;           // 8-row chunk base
            gload16(Ah + (size_t)(m0 + R + lr8) * KDIM + kc + ud * 8,
                    (char*)sA + R * 128);
            gload16(Bh + (size_t)(n0 + R + lr8) * KDIM + kc + ud * 8,
                    (char*)sB + R * 128);
        }
        __syncthreads();   // staging complete
        #pragma unroll
        for (int kk = 0; kk < 2; ++kk) {
            short8 a[4], b[4];
            int u = kk * 4 + kg;
            #pragma unroll
            for (int i = 0; i < 4; ++i) {
                int ra = wr * 64 + i * 16 + c;
                a[i] = *(const short8*)(sA + ra * 64 + u * 8);
                int rb = wc * 64 + i * 16 + c;
                b[i] = *(const short8*)(sB + rb * 64 + u * 8);
            }
            #pragma unroll
            for (int i = 0; i < 4; ++i)
                #pragma unroll
                for (int j = 0; j < 4; ++j)
                    acc[i][j] = __builtin_amdgcn_mfma_f32_16x16x32_bf16(
                        a[i], b[j], acc[i][j], 0, 0, 0);
        }
    }

    // ---- per-row top-4 over this block's 128 cols (packed-key extract) ----
    // key = ((as_uint(v+2) - 0x3F800000) << 7) | col7 ; monotone in v,
    // unique per col; quantization <= 2.4e-7 (covered by exact rerank).
    __syncthreads();                       // done reading tiles; reuse LDS
    unsigned* mk = (unsigned*)sA;          // [128][2][4] keys
    #pragma unroll
    for (int i = 0; i < 4; ++i) {
        #pragma unroll
        for (int r = 0; r < 4; ++r) {
            unsigned k0 = ((__float_as_uint(acc[i][0][r] + 2.0f) - 0x3F800000u) << 7)
                          | (unsigned)(wc * 64 + 0 * 16 + c);
            unsigned k1 = ((__float_as_uint(acc[i][1][r] + 2.0f) - 0x3F800000u) << 7)
                          | (unsigned)(wc * 64 + 1 * 16 + c);
            unsigned k2 = ((__float_as_uint(acc[i][2][r] + 2.0f) - 0x3F800000u) << 7)
                          | (unsigned)(wc * 64 + 2 * 16 + c);
            unsigned k3 = ((__float_as_uint(acc[i][3][r] + 2.0f) - 0x3F800000u) << 7)
                          | (unsigned)(wc * 64 + 3 * 16 + c);
            unsigned top[4];
            #pragma unroll
            for (int p = 0; p < 4; ++p) {
                unsigned m01 = k0 > k1 ? k0 : k1;
                unsigned m23 = k2 > k3 ? k2 : k3;
                unsigned m   = m01 > m23 ? m01 : m23;
                m = rowmax16(m);           // VALU DPP, no DS ops
                top[p] = m;
                k0 = (k0 == m) ? 0u : k0;
                k1 = (k1 == m) ? 0u : k1;
                k2 = (k2 == m) ? 0u : k2;
                k3 = (k3 == m) ? 0u : k3;
            }
            if (c == 0) {
                int row = wr * 64 + i * 16 + kg * 4 + r;
                *(uint4*)&mk[(row * 2 + wc) * 4] =
                    make_uint4(top[0], top[1], top[2], top[3]);
            }
        }
    }
    __syncthreads();
    if (tid < 128) {
        unsigned e[8];
        *(uint4*)&e[0] = *(const uint4*)&mk[tid * 8];
        *(uint4*)&e[4] = *(const uint4*)&mk[tid * 8 + 4];
        float vv[4]; int ii[4];
        #pragma unroll
        for (int p = 0; p < 4; ++p) {
            unsigned m = e[0];
            #pragma unroll
            for (int t = 1; t < 8; ++t) m = e[t] > m ? e[t] : m;
            vv[p] = __uint_as_float((m >> 7) + 0x3F800000u) - 2.0f;
            ii[p] = n0 + (int)(m & 127u);
            #pragma unroll
            for (int t = 0; t < 8; ++t) e[t] = (e[t] == m) ? 0u : e[t];
        }
        size_t o = (size_t)(m0 + tid) * 256 + nx * 4;   // [row][64 blocks][4]
        *(float4*)&Pv[o] = make_float4(vv[0], vv[1], vv[2], vv[3]);
        *(int4*)  &Pi[o] = make_int4(ii[0], ii[1], ii[2], ii[3]);
    }
}

// ---- stage-2: butterfly-merge -> global top-8, exact f32 rerank of 8 -------
// Rerank reproduces round-1's exact arithmetic: per element round(a*ia),
// round(b*ib), then a strict sequential fmaf chain in k order.
__global__ __launch_bounds__(256) void merge8_kernel(
    const float* __restrict__ Pv, const int* __restrict__ Pi,
    const float* __restrict__ base, const float* __restrict__ real,
    const float* __restrict__ inv, int* __restrict__ out) {
    int row  = blockIdx.x * 4 + (threadIdx.x >> 6);
    int lane = threadIdx.x & 63;
    float4 pv = *(const float4*)(Pv + (size_t)row * 256 + lane * 4);
    int4   pi = *(const int4*)  (Pi + (size_t)row * 256 + lane * 4);
    float lv[4] = {pv.x, pv.y, pv.z, pv.w};
    int   li[4] = {pi.x, pi.y, pi.z, pi.w};

    int topi[8];
    #pragma unroll
    for (int half = 0; half < 2; ++half) {
        float v0 = -3.0e38f, v1 = -3.0e38f, v2 = -3.0e38f, v3 = -3.0e38f;
        int   i0 = 0x7fffffff, i1 = 0x7fffffff, i2 = 0x7fffffff, i3 = 0x7fffffff;
        #pragma unroll
        for (int e = 0; e < 4; ++e)
            ins4(lv[e], li[e], v0, i0, v1, i1, v2, i2, v3, i3);
        #pragma unroll
        for (int mask = 1; mask <= 32; mask <<= 1) {
            float ov0 = __shfl_xor(v0, mask), ov1 = __shfl_xor(v1, mask),
                  ov2 = __shfl_xor(v2, mask), ov3 = __shfl_xor(v3, mask);
            int   oi0 = __shfl_xor(i0, mask), oi1 = __shfl_xor(i1, mask),
                  oi2 = __shfl_xor(i2, mask), oi3 = __shfl_xor(i3, mask);
            ins4(ov0, oi0, v0, i0, v1, i1, v2, i2, v3, i3);
            ins4(ov1, oi1, v0, i0, v1, i1, v2, i2, v3, i3);
            ins4(ov2, oi2, v0, i0, v1, i1, v2, i2, v3, i3);
            ins4(ov3, oi3, v0, i0, v1, i1, v2, i2, v3, i3);
        }
        topi[half * 4 + 0] = i0; topi[half * 4 + 1] = i1;
        topi[half * 4 + 2] = i2; topi[half * 4 + 3] = i3;
        if (half == 0) {
            #pragma unroll
            for (int e = 0; e < 4; ++e) {
                bool hit = (li[e] == i0) | (li[e] == i1) |
                           (li[e] == i2) | (li[e] == i3);
                lv[e] = hit ? -3.0e38f : lv[e];
            }
        }
    }

    // exact f32 re-rank of the 8 candidates (one per lane 0..7)
    int cand = topi[0];
    #pragma unroll
    for (int l = 1; l < 8; ++l) cand = (lane == l) ? topi[l] : cand;
    float s = 0.0f;
    if (lane < 8) {
        const float* a = base + (size_t)row  * KDIM;
        const float* b = real + (size_t)cand * KDIM;
        float ia = inv[row], ib = inv[NB + cand];
        #pragma unroll 4
        for (int k = 0; k < KDIM; k += 4) {
            float4 av = *(const float4*)(a + k);
            float4 bv = *(const float4*)(b + k);
            s = fmaf(av.x * ia, bv.x * ib, s);
            s = fmaf(av.y * ia, bv.y * ib, s);
            s = fmaf(av.z * ia, bv.z * ib, s);
            s = fmaf(av.w * ia, bv.w * ib, s);
        }
    }
    float fv0 = -3.0e38f, fv1 = -3.0e38f, fv2 = -3.0e38f;
    int   fi0 = 0x7fffffff, fi1 = 0x7fffffff, fi2 = 0x7fffffff;
    #pragma unroll
    for (int l = 0; l < 8; ++l) {
        float sv = __shfl(s, l);
        int   si = __shfl(cand, l);
        ins3(sv, si, fv0, fi0, fv1, fi1, fv2, fi2);
    }
    if (lane == 0) {
        out[row * 3 + 0] = fi0;
        out[row * 3 + 1] = fi1;
        out[row * 3 + 2] = fi2;
    }
}

// ======================= fallback (round-1 f32 path) ========================
__global__ __launch_bounds__(256) void norm_kernel(const float* __restrict__ base,
                                                   const float* __restrict__ real,
                                                   float* __restrict__ inv) {
    int rid  = blockIdx.x * 4 + (threadIdx.x >> 6);
    int lane = threadIdx.x & 63;
    if (rid >= NB + NR) return;
    const float* src = (rid < NB) ? (base + (size_t)rid * KDIM)
                                  : (real + (size_t)(rid - NB) * KDIM);
    float4 v = *(const float4*)(src + lane * 4);
    float ss = v.x * v.x + v.y * v.y + v.z * v.z + v.w * v.w;
    #pragma unroll
    for (int off = 32; off > 0; off >>= 1) ss += __shfl_xor(ss, off);
    if (lane == 0) inv[rid] = 1.0f / fmaxf(sqrtf(ss), 1e-12f);
}

#define DOT(i, j, av, bv)                                                      \
    acc[i][j] = fmaf(av.x, bv.x, acc[i][j]);                                   \
    acc[i][j] = fmaf(av.y, bv.y, acc[i][j]);                                   \
    acc[i][j] = fmaf(av.z, bv.z, acc[i][j]);                                   \
    acc[i][j] = fmaf(av.w, bv.w, acc[i][j]);

__global__ __launch_bounds__(256) void simtopk_kernel(
    const float* __restrict__ A, const float* __restrict__ B,
    const float* __restrict__ invA, const float* __restrict__ invB,
    int* __restrict__ out) {
    __shared__ float sA[64 * 68];
    __shared__ float sB[64 * 68];
    const int tid = threadIdx.x;
    const int tx  = tid & 15;
    const int ty4 = (tid >> 4) << 2;
    const int m0  = blockIdx.x * 64;
    float t3v[4][3];
    int   t3i[4][3];
    #pragma unroll
    for (int i = 0; i < 4; ++i)
        #pragma unroll
        for (int s = 0; s < 3; ++s) { t3v[i][s] = -3.0e38f; t3i[i][s] = 0x7fffffff; }
    for (int nn0 = 0; nn0 < NR; nn0 += 64) {
        float acc[4][4] = {{0.f}};
        for (int kc = 0; kc < KDIM; kc += 64) {
            __syncthreads();
            #pragma unroll
            for (int p = 0; p < 4; ++p) {
                int f = tid + (p << 8), row = f >> 4, c4 = (f & 15) << 2;
                float4 va = *(const float4*)(A + (size_t)(m0 + row) * KDIM + kc + c4);
                float  sa = invA[m0 + row];
                va.x *= sa; va.y *= sa; va.z *= sa; va.w *= sa;
                *(float4*)&sA[row * 68 + c4] = va;
                float4 vb = *(const float4*)(B + (size_t)(nn0 + row) * KDIM + kc + c4);
                float  sb = invB[nn0 + row];
                vb.x *= sb; vb.y *= sb; vb.z *= sb; vb.w *= sb;
                *(float4*)&sB[row * 68 + c4] = vb;
            }
            __syncthreads();
            #pragma unroll
            for (int k = 0; k < 64; k += 4) {
                float4 a0 = *(const float4*)&sA[(ty4 + 0) * 68 + k];
                float4 a1 = *(const float4*)&sA[(ty4 + 1) * 68 + k];
                float4 a2 = *(const float4*)&sA[(ty4 + 2) * 68 + k];
                float4 a3 = *(const float4*)&sA[(ty4 + 3) * 68 + k];
                float4 b0 = *(const float4*)&sB[(tx +  0) * 68 + k];
                float4 b1 = *(const float4*)&sB[(tx + 16) * 68 + k];
                float4 b2 = *(const float4*)&sB[(tx + 32) * 68 + k];
                float4 b3 = *(const float4*)&sB[(tx + 48) * 68 + k];
                DOT(0,0,a0,b0) DOT(0,1,a0,b1) DOT(0,2,a0,b2) DOT(0,3,a0,b3)
                DOT(1,0,a1,b0) DOT(1,1,a1,b1) DOT(1,2,a1,b2) DOT(1,3,a1,b3)
                DOT(2,0,a2,b0) DOT(2,1,a2,b1) DOT(2,2,a2,b2) DOT(2,3,a2,b3)
                DOT(3,0,a3,b0) DOT(3,1,a3,b1) DOT(3,2,a3,b2) DOT(3,3,a3,b3)
            }
        }
        #pragma unroll
        for (int i = 0; i < 4; ++i)
            #pragma unroll
            for (int j = 0; j < 4; ++j)
                ins3(acc[i][j], nn0 + tx + 16 * j,
                     t3v[i][0], t3i[i][0], t3v[i][1], t3i[i][1], t3v[i][2], t3i[i][2]);
    }
    __syncthreads();
    float* mv = sA;
    int*   mi = (int*)sB;
    #pragma unroll
    for (int i = 0; i < 4; ++i)
        #pragma unroll
        for (int s = 0; s < 3; ++s) {
            mv[(ty4 + i) * 48 + tx * 3 + s] = t3v[i][s];
            mi[(ty4 + i) * 48 + tx * 3 + s] = t3i[i][s];
        }
    __syncthreads();
    if (tid < 64) {
        float v0 = -3.0e38f, v1 = -3.0e38f, v2 = -3.0e38f;
        int   i0 = 0x7fffffff, i1 = 0x7fffffff, i2 = 0x7fffffff;
        for (int e = 0; e < 48; ++e)
            ins3(mv[tid * 48 + e], mi[tid * 48 + e], v0, i0, v1, i1, v2, i2);
        out[(m0 + tid) * 3 + 0] = i0;
        out[(m0 + tid) * 3 + 1] = i1;
        out[(m0 + tid) * 3 + 2] = i2;
    }
}

// ============================================================== launcher ====
extern "C" void kernel_launch(void* const* d_in, const int* in_sizes, int n_in,
                              void* d_out, int out_size, void* d_ws, size_t ws_size,
                              hipStream_t stream) {
    const float* base = (const float*)d_in[0];
    const float* real = (const float*)d_in[1];
    int* out = (int*)d_out;

    const size_t szAh  = (size_t)NB * KDIM * 2;      // 8.4 MB
    const size_t szBh  = (size_t)NR * KDIM * 2;      // 4.2 MB
    const size_t szPv  = (size_t)NB * 256 * 4;       // 16.8 MB
    const size_t szInv = (size_t)(NB + NR) * 4;      // 0.1 MB
    const size_t need  = szAh + szBh + 2 * szPv + szInv;

    if (ws_size >= need) {
        char* p = (char*)d_ws;
        ushort_t* Ah  = (ushort_t*)(p);
        ushort_t* Bh  = (ushort_t*)(p + szAh);
        float*    Pv  = (float*)   (p + szAh + szBh);
        int*      Pi  = (int*)     (p + szAh + szBh + szPv);
        float*    inv = (float*)   (p + szAh + szBh + 2 * szPv);

        hipLaunchKernelGGL(split_h_kernel, dim3((NB + NR) / 4), dim3(256), 0, stream,
                           base, real, Ah, Bh, inv);
        hipLaunchKernelGGL(mfma_topk_kernel, dim3(NR / 128, NB / 128), dim3(256), 0,
                           stream, Ah, Bh, Pv, Pi);
        hipLaunchKernelGGL(merge8_kernel, dim3(NB / 4), dim3(256), 0, stream,
                           Pv, Pi, base, real, inv, out);
    } else {
        float* inv = (float*)d_ws;
        hipLaunchKernelGGL(norm_kernel, dim3((NB + NR) / 4), dim3(256), 0, stream,
                           base, real, inv);
        hipLaunchKernelGGL(simtopk_kernel, dim3(NB / 64), dim3(256), 0, stream,
                           base, real, inv, inv + NB, out);
    }
}

// Round 9
// 251.309 us; speedup vs baseline: 3.7360x; 1.0255x over previous
//
#include <hip/hip_runtime.h>

#define KDIM 256
#define NB 16384
#define NR 8192

typedef unsigned short ushort_t;
typedef __attribute__((ext_vector_type(8))) short short8;
typedef __attribute__((ext_vector_type(4))) float f32x4;

// ---------------------------------------------------------------- helpers ---
__device__ __forceinline__ ushort_t f2bf(float f) {          // RNE f32->bf16
    unsigned u = __float_as_uint(f);
    unsigned r = (u + 0x7fffu + ((u >> 16) & 1u)) >> 16;
    return (ushort_t)r;
}
__device__ __forceinline__ void gload16(const void* g, void* l) {
    __builtin_amdgcn_global_load_lds(
        (const __attribute__((address_space(1))) void*)g,
        (__attribute__((address_space(3))) void*)l, 16, 0, 0);
}
// 16-lane all-reduce max on the VALU pipe: v_max through DPP row rotations
__device__ __forceinline__ unsigned rowmax16(unsigned m) {
    unsigned t;
    t = (unsigned)__builtin_amdgcn_update_dpp(0, (int)m, 0x121, 0xf, 0xf, true);
    m = t > m ? t : m;
    t = (unsigned)__builtin_amdgcn_update_dpp(0, (int)m, 0x122, 0xf, 0xf, true);
    m = t > m ? t : m;
    t = (unsigned)__builtin_amdgcn_update_dpp(0, (int)m, 0x124, 0xf, 0xf, true);
    m = t > m ? t : m;
    t = (unsigned)__builtin_amdgcn_update_dpp(0, (int)m, 0x128, 0xf, 0xf, true);
    m = t > m ? t : m;
    return m;
}
// branchless insert into sorted top-3 (v desc, idx asc on ties)
__device__ __forceinline__ void ins3(float v, int idx,
                                     float& v0, int& i0, float& v1, int& i1,
                                     float& v2, int& i2) {
    bool b0 = (v > v0) | ((v == v0) & (idx < i0));
    bool b1 = (v > v1) | ((v == v1) & (idx < i1));
    bool b2 = (v > v2) | ((v == v2) & (idx < i2));
    float nv2 = b1 ? v1 : (b2 ? v : v2);
    int   ni2 = b1 ? i1 : (b2 ? idx : i2);
    float nv1 = b0 ? v0 : (b1 ? v : v1);
    int   ni1 = b0 ? i0 : (b1 ? idx : i1);
    float nv0 = b0 ? v : v0;
    int   ni0 = b0 ? idx : i0;
    v0 = nv0; i0 = ni0; v1 = nv1; i1 = ni1; v2 = nv2; i2 = ni2;
}
// branchless insert into sorted top-4
__device__ __forceinline__ void ins4(float v, int idx,
                                     float& v0, int& i0, float& v1, int& i1,
                                     float& v2, int& i2, float& v3, int& i3) {
    bool b0 = (v > v0) | ((v == v0) & (idx < i0));
    bool b1 = (v > v1) | ((v == v1) & (idx < i1));
    bool b2 = (v > v2) | ((v == v2) & (idx < i2));
    bool b3 = (v > v3) | ((v == v3) & (idx < i3));
    float nv3 = b2 ? v2 : (b3 ? v : v3);
    int   ni3 = b2 ? i2 : (b3 ? idx : i3);
    float nv2 = b1 ? v1 : (b2 ? v : v2);
    int   ni2 = b1 ? i1 : (b2 ? idx : i2);
    float nv1 = b0 ? v0 : (b1 ? v : v1);
    int   ni1 = b0 ? i0 : (b1 ? idx : i1);
    float nv0 = b0 ? v : v0;
    int   ni0 = b0 ? idx : i0;
    v0 = nv0; i0 = ni0; v1 = nv1; i1 = ni1; v2 = nv2; i2 = ni2; v3 = nv3; i3 = ni3;
}

// ----------------- split: normalize + single bf16 (h) conversion ------------
__global__ __launch_bounds__(256) void split_h_kernel(
    const float* __restrict__ base, const float* __restrict__ real,
    ushort_t* __restrict__ Ah, ushort_t* __restrict__ Bh,
    float* __restrict__ inv) {
    int rid  = blockIdx.x * 4 + (threadIdx.x >> 6);
    int lane = threadIdx.x & 63;
    bool isA = rid < NB;
    int  row = isA ? rid : rid - NB;
    const float* src = isA ? base + (size_t)row * KDIM : real + (size_t)row * KDIM;
    float4 v = *(const float4*)(src + lane * 4);
    float ss = v.x * v.x + v.y * v.y + v.z * v.z + v.w * v.w;
    #pragma unroll
    for (int off = 32; off > 0; off >>= 1) ss += __shfl_xor(ss, off);
    float invn = 1.0f / fmaxf(sqrtf(ss), 1e-12f);

    ushort4 h4 = make_ushort4(f2bf(v.x * invn), f2bf(v.y * invn),
                              f2bf(v.z * invn), f2bf(v.w * invn));
    *(ushort4*)((isA ? Ah : Bh) + (size_t)row * KDIM + lane * 4) = h4;
    if (lane == 0) inv[rid] = invn;
}

// --------------------- bf16 MFMA GEMM (K=256) + per-block top-4 -------------
// block 256 thr = 4 waves (2x2), tile 128x128, BK=64, 4 K-iterations.
// K-loop: prefetch double-buffer (issue next-tile gload_lds BEFORE compute;
// one __syncthreads per iter — its vmcnt(0) drain lands after compute).
// Epilogue: packed-key (value<<7 | col) u32 max-extract, DPP row-max.
__global__ __launch_bounds__(256) void mfma_topk_kernel(
    const ushort_t* __restrict__ Ah, const ushort_t* __restrict__ Bh,
    float* __restrict__ Pv, int* __restrict__ Pi) {
    __shared__ ushort_t sA[2][128 * 64];
    __shared__ ushort_t sB[2][128 * 64];

    const int tid  = threadIdx.x;
    const int lane = tid & 63;
    const int w    = tid >> 6;
    const int wr   = w >> 1, wc = w & 1;
    const int c    = lane & 15;       // frag col/row-in-16
    const int kg   = lane >> 4;       // frag k-group (0..3)
    const int lr8  = lane >> 3;       // staging: row within 8-row chunk
    const int ud   = lane & 7;        // staging: 16B slot within row (linear)

    // ---- bijective XCD supertile remap: 8192 blocks = 8 XCD x 16 st x 8x8 --
    int lin = blockIdx.y * 64 + blockIdx.x;     // gridDim = (64, 128)
    int xcd = lin & 7;
    int pos = lin >> 3;                          // 0..1023
    int gg  = xcd * 1024 + pos;                  // chunked per-XCD range
    int st  = gg >> 6, in8 = gg & 63;            // supertile id, pos within
    int my  = ((st >> 3) << 3) + (in8 >> 3);     // 0..127 row tile
    int nx  = ((st & 7) << 3) + (in8 & 7);       // 0..63  col tile
    const int m0 = my * 128;
    const int n0 = nx * 128;

    f32x4 acc[4][4];
    #pragma unroll
    for (int i = 0; i < 4; ++i)
        #pragma unroll
        for (int j = 0; j < 4; ++j) acc[i][j] = (f32x4){0.f, 0.f, 0.f, 0.f};

    // prologue: stage tile 0 into buffer 0
    #pragma unroll
    for (int q = 0; q < 4; ++q) {
        int R = (w * 4 + q) * 8;
        gload16(Ah + (size_t)(m0 + R + lr8) * KDIM + ud * 8,
                (char*)sA[0] + R * 128);
        gload16(Bh + (size_t)(n0 + R + lr8) * KDIM + ud * 8,
                (char*)sB[0] + R * 128);
    }
    __syncthreads();                     // tile 0 resident

    #pragma unroll
    for (int t = 0; t < 4; ++t) {
        const int cur = t & 1;
        if (t < 3) {                     // issue next-tile loads (no wait)
            const int kc = (t + 1) * 64;
            ushort_t* dA = sA[cur ^ 1];
            ushort_t* dB = sB[cur ^ 1];
            #pragma unroll
            for (int q = 0; q < 4; ++q) {
                int R = (w * 4 + q) * 8;
                gload16(Ah + (size_t)(m0 + R + lr8) * KDIM + kc + ud * 8,
                        (char*)dA + R * 128);
                gload16(Bh + (size_t)(n0 + R + lr8) * KDIM + kc + ud * 8,
                        (char*)dB + R * 128);
            }
        }
        const ushort_t* rA = sA[cur];
        const ushort_t* rB = sB[cur];
        #pragma unroll
        for (int kk = 0; kk < 2; ++kk) {
            short8 a[4], b[4];
            int u = kk * 4 + kg;
            #pragma unroll
            for (int i = 0; i < 4; ++i) {
                int ra = wr * 64 + i * 16 + c;
                a[i] = *(const short8*)(rA + ra * 64 + u * 8);
                int rb = wc * 64 + i * 16 + c;
                b[i] = *(const short8*)(rB + rb * 64 + u * 8);
            }
            #pragma unroll
            for (int i = 0; i < 4; ++i)
                #pragma unroll
                for (int j = 0; j < 4; ++j)
                    acc[i][j] = __builtin_amdgcn_mfma_f32_16x16x32_bf16(
                        a[i], b[j], acc[i][j], 0, 0, 0);
        }
        __syncthreads();   // drains prefetch (vmcnt 0) + guards buf reuse
    }

    // ---- per-row top-4 over this block's 128 cols (packed-key extract) ----
    // key = ((as_uint(v+2) - 0x3F800000) << 7) | col7 ; monotone in v,
    // unique per col; quantization <= 2.4e-7 (covered by exact rerank).
    unsigned* mk = (unsigned*)sA;          // [128][2][4] keys (LDS reuse)
    #pragma unroll
    for (int i = 0; i < 4; ++i) {
        #pragma unroll
        for (int r = 0; r < 4; ++r) {
            unsigned k0 = ((__float_as_uint(acc[i][0][r] + 2.0f) - 0x3F800000u) << 7)
                          | (unsigned)(wc * 64 + 0 * 16 + c);
            unsigned k1 = ((__float_as_uint(acc[i][1][r] + 2.0f) - 0x3F800000u) << 7)
                          | (unsigned)(wc * 64 + 1 * 16 + c);
            unsigned k2 = ((__float_as_uint(acc[i][2][r] + 2.0f) - 0x3F800000u) << 7)
                          | (unsigned)(wc * 64 + 2 * 16 + c);
            unsigned k3 = ((__float_as_uint(acc[i][3][r] + 2.0f) - 0x3F800000u) << 7)
                          | (unsigned)(wc * 64 + 3 * 16 + c);
            unsigned top[4];
            #pragma unroll
            for (int p = 0; p < 4; ++p) {
                unsigned m01 = k0 > k1 ? k0 : k1;
                unsigned m23 = k2 > k3 ? k2 : k3;
                unsigned m   = m01 > m23 ? m01 : m23;
                m = rowmax16(m);           // VALU DPP, no DS ops
                top[p] = m;
                k0 = (k0 == m) ? 0u : k0;
                k1 = (k1 == m) ? 0u : k1;
                k2 = (k2 == m) ? 0u : k2;
                k3 = (k3 == m) ? 0u : k3;
            }
            if (c == 0) {
                int row = wr * 64 + i * 16 + kg * 4 + r;
                *(uint4*)&mk[(row * 2 + wc) * 4] =
                    make_uint4(top[0], top[1], top[2], top[3]);
            }
        }
    }
    __syncthreads();
    if (tid < 128) {
        unsigned e[8];
        *(uint4*)&e[0] = *(const uint4*)&mk[tid * 8];
        *(uint4*)&e[4] = *(const uint4*)&mk[tid * 8 + 4];
        float vv[4]; int ii[4];
        #pragma unroll
        for (int p = 0; p < 4; ++p) {
            unsigned m = e[0];
            #pragma unroll
            for (int t = 1; t < 8; ++t) m = e[t] > m ? e[t] : m;
            vv[p] = __uint_as_float((m >> 7) + 0x3F800000u) - 2.0f;
            ii[p] = n0 + (int)(m & 127u);
            #pragma unroll
            for (int t = 0; t < 8; ++t) e[t] = (e[t] == m) ? 0u : e[t];
        }
        size_t o = (size_t)(m0 + tid) * 256 + nx * 4;   // [row][64 blocks][4]
        *(float4*)&Pv[o] = make_float4(vv[0], vv[1], vv[2], vv[3]);
        *(int4*)  &Pi[o] = make_int4(ii[0], ii[1], ii[2], ii[3]);
    }
}

// ---- stage-2: butterfly-merge -> global top-8, exact f32 rerank of 8 -------
// Rerank reproduces round-1's exact arithmetic: per element round(a*ia),
// round(b*ib), then a strict sequential fmaf chain in k order.
__global__ __launch_bounds__(256) void merge8_kernel(
    const float* __restrict__ Pv, const int* __restrict__ Pi,
    const float* __restrict__ base, const float* __restrict__ real,
    const float* __restrict__ inv, int* __restrict__ out) {
    int row  = blockIdx.x * 4 + (threadIdx.x >> 6);
    int lane = threadIdx.x & 63;
    float4 pv = *(const float4*)(Pv + (size_t)row * 256 + lane * 4);
    int4   pi = *(const int4*)  (Pi + (size_t)row * 256 + lane * 4);
    float lv[4] = {pv.x, pv.y, pv.z, pv.w};
    int   li[4] = {pi.x, pi.y, pi.z, pi.w};

    int topi[8];
    #pragma unroll
    for (int half = 0; half < 2; ++half) {
        float v0 = -3.0e38f, v1 = -3.0e38f, v2 = -3.0e38f, v3 = -3.0e38f;
        int   i0 = 0x7fffffff, i1 = 0x7fffffff, i2 = 0x7fffffff, i3 = 0x7fffffff;
        #pragma unroll
        for (int e = 0; e < 4; ++e)
            ins4(lv[e], li[e], v0, i0, v1, i1, v2, i2, v3, i3);
        #pragma unroll
        for (int mask = 1; mask <= 32; mask <<= 1) {
            float ov0 = __shfl_xor(v0, mask), ov1 = __shfl_xor(v1, mask),
                  ov2 = __shfl_xor(v2, mask), ov3 = __shfl_xor(v3, mask);
            int   oi0 = __shfl_xor(i0, mask), oi1 = __shfl_xor(i1, mask),
                  oi2 = __shfl_xor(i2, mask), oi3 = __shfl_xor(i3, mask);
            ins4(ov0, oi0, v0, i0, v1, i1, v2, i2, v3, i3);
            ins4(ov1, oi1, v0, i0, v1, i1, v2, i2, v3, i3);
            ins4(ov2, oi2, v0, i0, v1, i1, v2, i2, v3, i3);
            ins4(ov3, oi3, v0, i0, v1, i1, v2, i2, v3, i3);
        }
        topi[half * 4 + 0] = i0; topi[half * 4 + 1] = i1;
        topi[half * 4 + 2] = i2; topi[half * 4 + 3] = i3;
        if (half == 0) {
            #pragma unroll
            for (int e = 0; e < 4; ++e) {
                bool hit = (li[e] == i0) | (li[e] == i1) |
                           (li[e] == i2) | (li[e] == i3);
                lv[e] = hit ? -3.0e38f : lv[e];
            }
        }
    }

    // exact f32 re-rank of the 8 candidates (one per lane 0..7)
    int cand = topi[0];
    #pragma unroll
    for (int l = 1; l < 8; ++l) cand = (lane == l) ? topi[l] : cand;
    float s = 0.0f;
    if (lane < 8) {
        const float* a = base + (size_t)row  * KDIM;
        const float* b = real + (size_t)cand * KDIM;
        float ia = inv[row], ib = inv[NB + cand];
        #pragma unroll 4
        for (int k = 0; k < KDIM; k += 4) {
            float4 av = *(const float4*)(a + k);
            float4 bv = *(const float4*)(b + k);
            s = fmaf(av.x * ia, bv.x * ib, s);
            s = fmaf(av.y * ia, bv.y * ib, s);
            s = fmaf(av.z * ia, bv.z * ib, s);
            s = fmaf(av.w * ia, bv.w * ib, s);
        }
    }
    float fv0 = -3.0e38f, fv1 = -3.0e38f, fv2 = -3.0e38f;
    int   fi0 = 0x7fffffff, fi1 = 0x7fffffff, fi2 = 0x7fffffff;
    #pragma unroll
    for (int l = 0; l < 8; ++l) {
        float sv = __shfl(s, l);
        int   si = __shfl(cand, l);
        ins3(sv, si, fv0, fi0, fv1, fi1, fv2, fi2);
    }
    if (lane == 0) {
        out[row * 3 + 0] = fi0;
        out[row * 3 + 1] = fi1;
        out[row * 3 + 2] = fi2;
    }
}

// ======================= fallback (round-1 f32 path) ========================
__global__ __launch_bounds__(256) void norm_kernel(const float* __restrict__ base,
                                                   const float* __restrict__ real,
                                                   float* __restrict__ inv) {
    int rid  = blockIdx.x * 4 + (threadIdx.x >> 6);
    int lane = threadIdx.x & 63;
    if (rid >= NB + NR) return;
    const float* src = (rid < NB) ? (base + (size_t)rid * KDIM)
                                  : (real + (size_t)(rid - NB) * KDIM);
    float4 v = *(const float4*)(src + lane * 4);
    float ss = v.x * v.x + v.y * v.y + v.z * v.z + v.w * v.w;
    #pragma unroll
    for (int off = 32; off > 0; off >>= 1) ss += __shfl_xor(ss, off);
    if (lane == 0) inv[rid] = 1.0f / fmaxf(sqrtf(ss), 1e-12f);
}

#define DOT(i, j, av, bv)                                                      \
    acc[i][j] = fmaf(av.x, bv.x, acc[i][j]);                                   \
    acc[i][j] = fmaf(av.y, bv.y, acc[i][j]);                                   \
    acc[i][j] = fmaf(av.z, bv.z, acc[i][j]);                                   \
    acc[i][j] = fmaf(av.w, bv.w, acc[i][j]);

__global__ __launch_bounds__(256) void simtopk_kernel(
    const float* __restrict__ A, const float* __restrict__ B,
    const float* __restrict__ invA, const float* __restrict__ invB,
    int* __restrict__ out) {
    __shared__ float sA[64 * 68];
    __shared__ float sB[64 * 68];
    const int tid = threadIdx.x;
    const int tx  = tid & 15;
    const int ty4 = (tid >> 4) << 2;
    const int m0  = blockIdx.x * 64;
    float t3v[4][3];
    int   t3i[4][3];
    #pragma unroll
    for (int i = 0; i < 4; ++i)
        #pragma unroll
        for (int s = 0; s < 3; ++s) { t3v[i][s] = -3.0e38f; t3i[i][s] = 0x7fffffff; }
    for (int nn0 = 0; nn0 < NR; nn0 += 64) {
        float acc[4][4] = {{0.f}};
        for (int kc = 0; kc < KDIM; kc += 64) {
            __syncthreads();
            #pragma unroll
            for (int p = 0; p < 4; ++p) {
                int f = tid + (p << 8), row = f >> 4, c4 = (f & 15) << 2;
                float4 va = *(const float4*)(A + (size_t)(m0 + row) * KDIM + kc + c4);
                float  sa = invA[m0 + row];
                va.x *= sa; va.y *= sa; va.z *= sa; va.w *= sa;
                *(float4*)&sA[row * 68 + c4] = va;
                float4 vb = *(const float4*)(B + (size_t)(nn0 + row) * KDIM + kc + c4);
                float  sb = invB[nn0 + row];
                vb.x *= sb; vb.y *= sb; vb.z *= sb; vb.w *= sb;
                *(float4*)&sB[row * 68 + c4] = vb;
            }
            __syncthreads();
            #pragma unroll
            for (int k = 0; k < 64; k += 4) {
                float4 a0 = *(const float4*)&sA[(ty4 + 0) * 68 + k];
                float4 a1 = *(const float4*)&sA[(ty4 + 1) * 68 + k];
                float4 a2 = *(const float4*)&sA[(ty4 + 2) * 68 + k];
                float4 a3 = *(const float4*)&sA[(ty4 + 3) * 68 + k];
                float4 b0 = *(const float4*)&sB[(tx +  0) * 68 + k];
                float4 b1 = *(const float4*)&sB[(tx + 16) * 68 + k];
                float4 b2 = *(const float4*)&sB[(tx + 32) * 68 + k];
                float4 b3 = *(const float4*)&sB[(tx + 48) * 68 + k];
                DOT(0,0,a0,b0) DOT(0,1,a0,b1) DOT(0,2,a0,b2) DOT(0,3,a0,b3)
                DOT(1,0,a1,b0) DOT(1,1,a1,b1) DOT(1,2,a1,b2) DOT(1,3,a1,b3)
                DOT(2,0,a2,b0) DOT(2,1,a2,b1) DOT(2,2,a2,b2) DOT(2,3,a2,b3)
                DOT(3,0,a3,b0) DOT(3,1,a3,b1) DOT(3,2,a3,b2) DOT(3,3,a3,b3)
            }
        }
        #pragma unroll
        for (int i = 0; i < 4; ++i)
            #pragma unroll
            for (int j = 0; j < 4; ++j)
                ins3(acc[i][j], nn0 + tx + 16 * j,
                     t3v[i][0], t3i[i][0], t3v[i][1], t3i[i][1], t3v[i][2], t3i[i][2]);
    }
    __syncthreads();
    float* mv = sA;
    int*   mi = (int*)sB;
    #pragma unroll
    for (int i = 0; i < 4; ++i)
        #pragma unroll
        for (int s = 0; s < 3; ++s) {
            mv[(ty4 + i) * 48 + tx * 3 + s] = t3v[i][s];
            mi[(ty4 + i) * 48 + tx * 3 + s] = t3i[i][s];
        }
    __syncthreads();
    if (tid < 64) {
        float v0 = -3.0e38f, v1 = -3.0e38f, v2 = -3.0e38f;
        int   i0 = 0x7fffffff, i1 = 0x7fffffff, i2 = 0x7fffffff;
        for (int e = 0; e < 48; ++e)
            ins3(mv[tid * 48 + e], mi[tid * 48 + e], v0, i0, v1, i1, v2, i2);
        out[(m0 + tid) * 3 + 0] = i0;
        out[(m0 + tid) * 3 + 1] = i1;
        out[(m0 + tid) * 3 + 2] = i2;
    }
}

// ============================================================== launcher ====
extern "C" void kernel_launch(void* const* d_in, const int* in_sizes, int n_in,
                              void* d_out, int out_size, void* d_ws, size_t ws_size,
                              hipStream_t stream) {
    const float* base = (const float*)d_in[0];
    const float* real = (const float*)d_in[1];
    int* out = (int*)d_out;

    const size_t szAh  = (size_t)NB * KDIM * 2;      // 8.4 MB
    const size_t szBh  = (size_t)NR * KDIM * 2;      // 4.2 MB
    const size_t szPv  = (size_t)NB * 256 * 4;       // 16.8 MB
    const size_t szInv = (size_t)(NB + NR) * 4;      // 0.1 MB
    const size_t need  = szAh + szBh + 2 * szPv + szInv;

    if (ws_size >= need) {
        char* p = (char*)d_ws;
        ushort_t* Ah  = (ushort_t*)(p);
        ushort_t* Bh  = (ushort_t*)(p + szAh);
        float*    Pv  = (float*)   (p + szAh + szBh);
        int*      Pi  = (int*)     (p + szAh + szBh + szPv);
        float*    inv = (float*)   (p + szAh + szBh + 2 * szPv);

        hipLaunchKernelGGL(split_h_kernel, dim3((NB + NR) / 4), dim3(256), 0, stream,
                           base, real, Ah, Bh, inv);
        hipLaunchKernelGGL(mfma_topk_kernel, dim3(NR / 128, NB / 128), dim3(256), 0,
                           stream, Ah, Bh, Pv, Pi);
        hipLaunchKernelGGL(merge8_kernel, dim3(NB / 4), dim3(256), 0, stream,
                           Pv, Pi, base, real, inv, out);
    } else {
        float* inv = (float*)d_ws;
        hipLaunchKernelGGL(norm_kernel, dim3((NB + NR) / 4), dim3(256), 0, stream,
                           base, real, inv);
        hipLaunchKernelGGL(simtopk_kernel, dim3(NB / 64), dim3(256), 0, stream,
                           base, real, inv, inv + NB, out);
    }
}

// Round 10
// 227.535 us; speedup vs baseline: 4.1264x; 1.1045x over previous
//
#include <hip/hip_runtime.h>

#define KDIM 256
#define NB 16384
#define NR 8192
#define CHUNK 1088            // 1024B data + 64B pad per 8-row chunk

typedef unsigned short ushort_t;
typedef unsigned long long u64;
typedef __attribute__((ext_vector_type(8))) short short8;
typedef __attribute__((ext_vector_type(4))) float f32x4;

// ---------------------------------------------------------------- helpers ---
__device__ __forceinline__ ushort_t f2bf(float f) {          // RNE f32->bf16
    unsigned u = __float_as_uint(f);
    unsigned r = (u + 0x7fffu + ((u >> 16) & 1u)) >> 16;
    return (ushort_t)r;
}
__device__ __forceinline__ void gload16(const void* g, void* l) {
    __builtin_amdgcn_global_load_lds(
        (const __attribute__((address_space(1))) void*)g,
        (__attribute__((address_space(3))) void*)l, 16, 0, 0);
}
// 16-lane all-reduce max on the VALU pipe: v_max through DPP row rotations
__device__ __forceinline__ unsigned rowmax16(unsigned m) {
    unsigned t;
    t = (unsigned)__builtin_amdgcn_update_dpp(0, (int)m, 0x121, 0xf, 0xf, true);
    m = t > m ? t : m;
    t = (unsigned)__builtin_amdgcn_update_dpp(0, (int)m, 0x122, 0xf, 0xf, true);
    m = t > m ? t : m;
    t = (unsigned)__builtin_amdgcn_update_dpp(0, (int)m, 0x124, 0xf, 0xf, true);
    m = t > m ? t : m;
    t = (unsigned)__builtin_amdgcn_update_dpp(0, (int)m, 0x128, 0xf, 0xf, true);
    m = t > m ? t : m;
    return m;
}
// branchless insert into sorted top-3 (v desc, idx asc on ties)
__device__ __forceinline__ void ins3(float v, int idx,
                                     float& v0, int& i0, float& v1, int& i1,
                                     float& v2, int& i2) {
    bool b0 = (v > v0) | ((v == v0) & (idx < i0));
    bool b1 = (v > v1) | ((v == v1) & (idx < i1));
    bool b2 = (v > v2) | ((v == v2) & (idx < i2));
    float nv2 = b1 ? v1 : (b2 ? v : v2);
    int   ni2 = b1 ? i1 : (b2 ? idx : i2);
    float nv1 = b0 ? v0 : (b1 ? v : v1);
    int   ni1 = b0 ? i0 : (b1 ? idx : i1);
    float nv0 = b0 ? v : v0;
    int   ni0 = b0 ? idx : i0;
    v0 = nv0; i0 = ni0; v1 = nv1; i1 = ni1; v2 = nv2; i2 = ni2;
}
// branchless insert into sorted top-3 (fallback helper kept for simtopk)
__device__ __forceinline__ void ins3f(float v, int idx,
                                      float* tv, int* ti) {
    ins3(v, idx, tv[0], ti[0], tv[1], ti[1], tv[2], ti[2]);
}

// ----------------- split: normalize + single bf16 (h) conversion ------------
__global__ __launch_bounds__(256) void split_h_kernel(
    const float* __restrict__ base, const float* __restrict__ real,
    ushort_t* __restrict__ Ah, ushort_t* __restrict__ Bh,
    float* __restrict__ inv) {
    int rid  = blockIdx.x * 4 + (threadIdx.x >> 6);
    int lane = threadIdx.x & 63;
    bool isA = rid < NB;
    int  row = isA ? rid : rid - NB;
    const float* src = isA ? base + (size_t)row * KDIM : real + (size_t)row * KDIM;
    float4 v = *(const float4*)(src + lane * 4);
    float ss = v.x * v.x + v.y * v.y + v.z * v.z + v.w * v.w;
    #pragma unroll
    for (int off = 32; off > 0; off >>= 1) ss += __shfl_xor(ss, off);
    float invn = 1.0f / fmaxf(sqrtf(ss), 1e-12f);

    ushort4 h4 = make_ushort4(f2bf(v.x * invn), f2bf(v.y * invn),
                              f2bf(v.z * invn), f2bf(v.w * invn));
    *(ushort4*)((isA ? Ah : Bh) + (size_t)row * KDIM + lane * 4) = h4;
    if (lane == 0) inv[rid] = invn;
}

// --------------------- bf16 MFMA GEMM (K=256) + per-block top-4 keys --------
// block 256 thr = 4 waves (2x2), tile 128x128, BK=64, 4 K-iterations,
// prefetch double-buffer. LDS: 8-row chunks padded to 1088B -> conflict-free
// frag reads (bank = 16*(ra>>3) + 4u mod 32, kg-groups disjoint). Staging
// stays linear per chunk (independent gload base per chunk).
// Epilogue: packed-key (val24<<7 | col7) u32 max-extract, DPP row-max; the
// per-(row,block) top-4 KEYS are written to Pk (col7 + slot position encode
// the global column; quantization 2.4e-7 covered by exact rerank).
__global__ __launch_bounds__(256) void mfma_topk_kernel(
    const ushort_t* __restrict__ Ah, const ushort_t* __restrict__ Bh,
    unsigned* __restrict__ Pk) {
    __shared__ char sAb[2][16 * CHUNK];
    __shared__ char sBb[2][16 * CHUNK];

    const int tid  = threadIdx.x;
    const int lane = tid & 63;
    const int w    = tid >> 6;
    const int wr   = w >> 1, wc = w & 1;
    const int c    = lane & 15;       // frag col/row-in-16
    const int kg   = lane >> 4;       // frag k-group (0..3)
    const int lr8  = lane >> 3;       // staging: row within 8-row chunk
    const int ud   = lane & 7;        // staging: 16B slot within row (linear)

    // ---- bijective XCD supertile remap: 8192 blocks = 8 XCD x 16 st x 8x8 --
    int lin = blockIdx.y * 64 + blockIdx.x;     // gridDim = (64, 128)
    int xcd = lin & 7;
    int pos = lin >> 3;                          // 0..1023
    int gg  = xcd * 1024 + pos;                  // chunked per-XCD range
    int st  = gg >> 6, in8 = gg & 63;            // supertile id, pos within
    int my  = ((st >> 3) << 3) + (in8 >> 3);     // 0..127 row tile
    int nx  = ((st & 7) << 3) + (in8 & 7);       // 0..63  col tile
    const int m0 = my * 128;
    const int n0 = nx * 128;

    f32x4 acc[4][4];
    #pragma unroll
    for (int i = 0; i < 4; ++i)
        #pragma unroll
        for (int j = 0; j < 4; ++j) acc[i][j] = (f32x4){0.f, 0.f, 0.f, 0.f};

    // prologue: stage tile 0 into buffer 0
    #pragma unroll
    for (int q = 0; q < 4; ++q) {
        int cq = w * 4 + q;                       // chunk id 0..15
        gload16(Ah + (size_t)(m0 + cq * 8 + lr8) * KDIM + ud * 8,
                sAb[0] + cq * CHUNK);
        gload16(Bh + (size_t)(n0 + cq * 8 + lr8) * KDIM + ud * 8,
                sBb[0] + cq * CHUNK);
    }
    __syncthreads();                     // tile 0 resident

    #pragma unroll
    for (int t = 0; t < 4; ++t) {
        const int cur = t & 1;
        if (t < 3) {                     // issue next-tile loads (no wait)
            const int kc = (t + 1) * 64;
            char* dA = sAb[cur ^ 1];
            char* dB = sBb[cur ^ 1];
            #pragma unroll
            for (int q = 0; q < 4; ++q) {
                int cq = w * 4 + q;
                gload16(Ah + (size_t)(m0 + cq * 8 + lr8) * KDIM + kc + ud * 8,
                        dA + cq * CHUNK);
                gload16(Bh + (size_t)(n0 + cq * 8 + lr8) * KDIM + kc + ud * 8,
                        dB + cq * CHUNK);
            }
        }
        const char* rA = sAb[cur];
        const char* rB = sBb[cur];
        #pragma unroll
        for (int kk = 0; kk < 2; ++kk) {
            short8 a[4], b[4];
            int u = kk * 4 + kg;
            #pragma unroll
            for (int i = 0; i < 4; ++i) {
                int ra = wr * 64 + i * 16 + c;
                a[i] = *(const short8*)(rA + (ra >> 3) * CHUNK +
                                        (ra & 7) * 128 + u * 16);
                int rb = wc * 64 + i * 16 + c;
                b[i] = *(const short8*)(rB + (rb >> 3) * CHUNK +
                                        (rb & 7) * 128 + u * 16);
            }
            #pragma unroll
            for (int i = 0; i < 4; ++i)
                #pragma unroll
                for (int j = 0; j < 4; ++j)
                    acc[i][j] = __builtin_amdgcn_mfma_f32_16x16x32_bf16(
                        a[i], b[j], acc[i][j], 0, 0, 0);
        }
        __syncthreads();   // drains prefetch (vmcnt 0) + guards buf reuse
    }

    // ---- per-row top-4 keys over this block's 128 cols ----
    unsigned* mk = (unsigned*)sAb;         // [128][2][4] keys (LDS reuse)
    #pragma unroll
    for (int i = 0; i < 4; ++i) {
        #pragma unroll
        for (int r = 0; r < 4; ++r) {
            unsigned k0 = ((__float_as_uint(acc[i][0][r] + 2.0f) - 0x3F800000u) << 7)
                          | (unsigned)(wc * 64 + 0 * 16 + c);
            unsigned k1 = ((__float_as_uint(acc[i][1][r] + 2.0f) - 0x3F800000u) << 7)
                          | (unsigned)(wc * 64 + 1 * 16 + c);
            unsigned k2 = ((__float_as_uint(acc[i][2][r] + 2.0f) - 0x3F800000u) << 7)
                          | (unsigned)(wc * 64 + 2 * 16 + c);
            unsigned k3 = ((__float_as_uint(acc[i][3][r] + 2.0f) - 0x3F800000u) << 7)
                          | (unsigned)(wc * 64 + 3 * 16 + c);
            unsigned top[4];
            #pragma unroll
            for (int p = 0; p < 4; ++p) {
                unsigned m01 = k0 > k1 ? k0 : k1;
                unsigned m23 = k2 > k3 ? k2 : k3;
                unsigned m   = m01 > m23 ? m01 : m23;
                m = rowmax16(m);           // VALU DPP, no DS ops
                top[p] = m;
                k0 = (k0 == m) ? 0u : k0;
                k1 = (k1 == m) ? 0u : k1;
                k2 = (k2 == m) ? 0u : k2;
                k3 = (k3 == m) ? 0u : k3;
            }
            if (c == 0) {
                int row = wr * 64 + i * 16 + kg * 4 + r;
                *(uint4*)&mk[(row * 2 + wc) * 4] =
                    make_uint4(top[0], top[1], top[2], top[3]);
            }
        }
    }
    __syncthreads();
    if (tid < 128) {
        unsigned e[8];
        *(uint4*)&e[0] = *(const uint4*)&mk[tid * 8];
        *(uint4*)&e[4] = *(const uint4*)&mk[tid * 8 + 4];
        unsigned top[4];
        #pragma unroll
        for (int p = 0; p < 4; ++p) {
            unsigned m = e[0];
            #pragma unroll
            for (int q = 1; q < 8; ++q) m = e[q] > m ? e[q] : m;
            top[p] = m;
            #pragma unroll
            for (int q = 0; q < 8; ++q) e[q] = (e[q] == m) ? 0u : e[q];
        }
        size_t o = (size_t)(m0 + tid) * 256 + nx * 4;   // [row][64 blocks][4]
        *(uint4*)&Pk[o] = make_uint4(top[0], top[1], top[2], top[3]);
    }
}

// ---- stage-2: u64-key butterfly -> global top-8, exact f32 rerank of 8 -----
// ekey = val24 << 13 | (8191 - idx): monotone in value, idx-asc on ties.
// Rerank reproduces round-1's exact arithmetic (sequential fmaf chain).
__global__ __launch_bounds__(256) void merge8_kernel(
    const unsigned* __restrict__ Pk,
    const float* __restrict__ base, const float* __restrict__ real,
    const float* __restrict__ inv, int* __restrict__ out) {
    int row  = blockIdx.x * 4 + (threadIdx.x >> 6);
    int lane = threadIdx.x & 63;
    uint4 kv = *(const uint4*)(Pk + (size_t)row * 256 + lane * 4);

    // expand to u64 keys with full global index (this lane's block nx == lane)
    u64 k[4];
    {
        unsigned kk[4] = {kv.x, kv.y, kv.z, kv.w};
        #pragma unroll
        for (int e = 0; e < 4; ++e) {
            int idx = lane * 128 + (int)(kk[e] & 127u);
            k[e] = ((u64)(kk[e] >> 7) << 13) | (unsigned)(8191 - idx);
        }
    }

    int cnd[8];
    #pragma unroll
    for (int p = 0; p < 8; ++p) {
        u64 m01 = k[0] > k[1] ? k[0] : k[1];
        u64 m23 = k[2] > k[3] ? k[2] : k[3];
        u64 m   = m01 > m23 ? m01 : m23;
        #pragma unroll
        for (int mask = 1; mask <= 32; mask <<= 1) {
            u64 om = __shfl_xor(m, mask);
            m = om > m ? om : m;
        }
        cnd[p] = 8191 - (int)(m & 8191u);
        #pragma unroll
        for (int e = 0; e < 4; ++e) k[e] = (k[e] == m) ? 0ull : k[e];
    }

    // exact f32 re-rank of the 8 candidates (one per lane 0..7)
    int cand = cnd[0];
    #pragma unroll
    for (int l = 1; l < 8; ++l) cand = (lane == l) ? cnd[l] : cand;
    float s = 0.0f;
    if (lane < 8) {
        const float* a = base + (size_t)row  * KDIM;
        const float* b = real + (size_t)cand * KDIM;
        float ia = inv[row], ib = inv[NB + cand];
        #pragma unroll 4
        for (int kq = 0; kq < KDIM; kq += 4) {
            float4 av = *(const float4*)(a + kq);
            float4 bv = *(const float4*)(b + kq);
            s = fmaf(av.x * ia, bv.x * ib, s);
            s = fmaf(av.y * ia, bv.y * ib, s);
            s = fmaf(av.z * ia, bv.z * ib, s);
            s = fmaf(av.w * ia, bv.w * ib, s);
        }
    }
    float fv0 = -3.0e38f, fv1 = -3.0e38f, fv2 = -3.0e38f;
    int   fi0 = 0x7fffffff, fi1 = 0x7fffffff, fi2 = 0x7fffffff;
    #pragma unroll
    for (int l = 0; l < 8; ++l) {
        float sv = __shfl(s, l);
        int   si = __shfl(cand, l);
        ins3(sv, si, fv0, fi0, fv1, fi1, fv2, fi2);
    }
    if (lane == 0) {
        out[row * 3 + 0] = fi0;
        out[row * 3 + 1] = fi1;
        out[row * 3 + 2] = fi2;
    }
}

// ======================= fallback (round-1 f32 path) ========================
__global__ __launch_bounds__(256) void norm_kernel(const float* __restrict__ base,
                                                   const float* __restrict__ real,
                                                   float* __restrict__ inv) {
    int rid  = blockIdx.x * 4 + (threadIdx.x >> 6);
    int lane = threadIdx.x & 63;
    if (rid >= NB + NR) return;
    const float* src = (rid < NB) ? (base + (size_t)rid * KDIM)
                                  : (real + (size_t)(rid - NB) * KDIM);
    float4 v = *(const float4*)(src + lane * 4);
    float ss = v.x * v.x + v.y * v.y + v.z * v.z + v.w * v.w;
    #pragma unroll
    for (int off = 32; off > 0; off >>= 1) ss += __shfl_xor(ss, off);
    if (lane == 0) inv[rid] = 1.0f / fmaxf(sqrtf(ss), 1e-12f);
}

#define DOT(i, j, av, bv)                                                      \
    acc[i][j] = fmaf(av.x, bv.x, acc[i][j]);                                   \
    acc[i][j] = fmaf(av.y, bv.y, acc[i][j]);                                   \
    acc[i][j] = fmaf(av.z, bv.z, acc[i][j]);                                   \
    acc[i][j] = fmaf(av.w, bv.w, acc[i][j]);

__global__ __launch_bounds__(256) void simtopk_kernel(
    const float* __restrict__ A, const float* __restrict__ B,
    const float* __restrict__ invA, const float* __restrict__ invB,
    int* __restrict__ out) {
    __shared__ float sA[64 * 68];
    __shared__ float sB[64 * 68];
    const int tid = threadIdx.x;
    const int tx  = tid & 15;
    const int ty4 = (tid >> 4) << 2;
    const int m0  = blockIdx.x * 64;
    float t3v[4][3];
    int   t3i[4][3];
    #pragma unroll
    for (int i = 0; i < 4; ++i)
        #pragma unroll
        for (int s = 0; s < 3; ++s) { t3v[i][s] = -3.0e38f; t3i[i][s] = 0x7fffffff; }
    for (int nn0 = 0; nn0 < NR; nn0 += 64) {
        float acc[4][4] = {{0.f}};
        for (int kc = 0; kc < KDIM; kc += 64) {
            __syncthreads();
            #pragma unroll
            for (int p = 0; p < 4; ++p) {
                int f = tid + (p << 8), row = f >> 4, c4 = (f & 15) << 2;
                float4 va = *(const float4*)(A + (size_t)(m0 + row) * KDIM + kc + c4);
                float  sa = invA[m0 + row];
                va.x *= sa; va.y *= sa; va.z *= sa; va.w *= sa;
                *(float4*)&sA[row * 68 + c4] = va;
                float4 vb = *(const float4*)(B + (size_t)(nn0 + row) * KDIM + kc + c4);
                float  sb = invB[nn0 + row];
                vb.x *= sb; vb.y *= sb; vb.z *= sb; vb.w *= sb;
                *(float4*)&sB[row * 68 + c4] = vb;
            }
            __syncthreads();
            #pragma unroll
            for (int k = 0; k < 64; k += 4) {
                float4 a0 = *(const float4*)&sA[(ty4 + 0) * 68 + k];
                float4 a1 = *(const float4*)&sA[(ty4 + 1) * 68 + k];
                float4 a2 = *(const float4*)&sA[(ty4 + 2) * 68 + k];
                float4 a3 = *(const float4*)&sA[(ty4 + 3) * 68 + k];
                float4 b0 = *(const float4*)&sB[(tx +  0) * 68 + k];
                float4 b1 = *(const float4*)&sB[(tx + 16) * 68 + k];
                float4 b2 = *(const float4*)&sB[(tx + 32) * 68 + k];
                float4 b3 = *(const float4*)&sB[(tx + 48) * 68 + k];
                DOT(0,0,a0,b0) DOT(0,1,a0,b1) DOT(0,2,a0,b2) DOT(0,3,a0,b3)
                DOT(1,0,a1,b0) DOT(1,1,a1,b1) DOT(1,2,a1,b2) DOT(1,3,a1,b3)
                DOT(2,0,a2,b0) DOT(2,1,a2,b1) DOT(2,2,a2,b2) DOT(2,3,a2,b3)
                DOT(3,0,a3,b0) DOT(3,1,a3,b1) DOT(3,2,a3,b2) DOT(3,3,a3,b3)
            }
        }
        #pragma unroll
        for (int i = 0; i < 4; ++i)
            #pragma unroll
            for (int j = 0; j < 4; ++j)
                ins3f(acc[i][j], nn0 + tx + 16 * j, t3v[i], t3i[i]);
    }
    __syncthreads();
    float* mv = sA;
    int*   mi = (int*)sB;
    #pragma unroll
    for (int i = 0; i < 4; ++i)
        #pragma unroll
        for (int s = 0; s < 3; ++s) {
            mv[(ty4 + i) * 48 + tx * 3 + s] = t3v[i][s];
            mi[(ty4 + i) * 48 + tx * 3 + s] = t3i[i][s];
        }
    __syncthreads();
    if (tid < 64) {
        float v0 = -3.0e38f, v1 = -3.0e38f, v2 = -3.0e38f;
        int   i0 = 0x7fffffff, i1 = 0x7fffffff, i2 = 0x7fffffff;
        for (int e = 0; e < 48; ++e)
            ins3(mv[tid * 48 + e], mi[tid * 48 + e], v0, i0, v1, i1, v2, i2);
        out[(m0 + tid) * 3 + 0] = i0;
        out[(m0 + tid) * 3 + 1] = i1;
        out[(m0 + tid) * 3 + 2] = i2;
    }
}

// ============================================================== launcher ====
extern "C" void kernel_launch(void* const* d_in, const int* in_sizes, int n_in,
                              void* d_out, int out_size, void* d_ws, size_t ws_size,
                              hipStream_t stream) {
    const float* base = (const float*)d_in[0];
    const float* real = (const float*)d_in[1];
    int* out = (int*)d_out;

    const size_t szAh  = (size_t)NB * KDIM * 2;      // 8.4 MB
    const size_t szBh  = (size_t)NR * KDIM * 2;      // 4.2 MB
    const size_t szPk  = (size_t)NB * 256 * 4;       // 16.8 MB
    const size_t szInv = (size_t)(NB + NR) * 4;      // 0.1 MB
    const size_t need  = szAh + szBh + szPk + szInv;

    if (ws_size >= need) {
        char* p = (char*)d_ws;
        ushort_t* Ah  = (ushort_t*)(p);
        ushort_t* Bh  = (ushort_t*)(p + szAh);
        unsigned* Pk  = (unsigned*)(p + szAh + szBh);
        float*    inv = (float*)   (p + szAh + szBh + szPk);

        hipLaunchKernelGGL(split_h_kernel, dim3((NB + NR) / 4), dim3(256), 0, stream,
                           base, real, Ah, Bh, inv);
        hipLaunchKernelGGL(mfma_topk_kernel, dim3(NR / 128, NB / 128), dim3(256), 0,
                           stream, Ah, Bh, Pk);
        hipLaunchKernelGGL(merge8_kernel, dim3(NB / 4), dim3(256), 0, stream,
                           Pk, base, real, inv, out);
    } else {
        float* inv = (float*)d_ws;
        hipLaunchKernelGGL(norm_kernel, dim3((NB + NR) / 4), dim3(256), 0, stream,
                           base, real, inv);
        hipLaunchKernelGGL(simtopk_kernel, dim3(NB / 64), dim3(256), 0, stream,
                           base, real, inv, inv + NB, out);
    }
}